// Round 8
// baseline (1754.083 us; speedup 1.0000x reference)
//
#include <hip/hip_runtime.h>

#define CIN_  128
#define C_    256
#define HW_   1024      /* 32*32 */
#define NPC_  65536.0f  /* 64*1024 elements per channel for BN stats */
#define NB_   16384     /* 64 batches * 256 channels */

constexpr size_t NELEM = 16777216ull;   // 64*256*32*32

// ---- module-scope device scratch: one buffer per producer (no reuse hazards)
__device__ float g_sel[8];
__device__ float g_stats[8 * 512];      // per-slot: [0..255]=sum, [256..511]=sumsq
__device__ int   g_isf32;
__device__ float g_h[NELEM];            // relu(BN0(trans))
__device__ float g_c3[NELEM];           // conv3x3 out      (slot 4)
__device__ float g_c5[NELEM];           // conv5x5 out      (slot 5)
__device__ float g_cd[NELEM];           // dil conv out     (slot 7)
__device__ float g_pm[NELEM];           // maxpool out      (slot 1)
__device__ float g_pa[NELEM];           // avgpool out      (slot 2)
__device__ float g_pw[NELEM];           // pointwise out    (slot 6)
__device__ float g_dw[NELEM];           // trans tmp, then depthwise out

// ---- prepass-converted f32 weights, packed co-fastest (16 per tap) ---------
// g_w5f: [cg=16][ci=256][tap=25][u=16]  (co = cg*16+u)
// g_w3f/g_wdf: [cg=16][ci=256][tap=9][u=16]
// g_wtf: [cg=16][ci=128][u=16]  g_wpf: [cg=16][ci=256][u=16]
__device__ float g_w5f[16 * 256 * 25 * 16];
__device__ float g_w3f[16 * 256 * 9 * 16];
__device__ float g_wdf[16 * 256 * 9 * 16];
__device__ float g_wtf[16 * 128 * 16];
__device__ float g_wpf[16 * 256 * 16];

__device__ __forceinline__ float u2f(unsigned short u) {
    union { unsigned int i; float f; } x; x.i = ((unsigned int)u) << 16; return x.f;
}
__device__ __forceinline__ unsigned short f2u(float f) {
    union { float f; unsigned int i; } x; x.f = f;
    unsigned int r = x.i + 0x7fffu + ((x.i >> 16) & 1u);  // RNE
    return (unsigned short)(r >> 16);
}
__device__ __forceinline__ float ldq(const void* p, long i, int isf32) {
    return isf32 ? ((const float*)p)[i] : u2f(((const unsigned short*)p)[i]);
}

// 64-FMA block shared by k_trans / k_pw (16 output channels x 4 pixels)
#define FMA16X4(acc, wq0, wq1, wq2, wq3, x0v, x1v, x2v, x3v)                                             \
    acc[ 0][0]+=x0v*wq0.x; acc[ 0][1]+=x1v*wq0.x; acc[ 0][2]+=x2v*wq0.x; acc[ 0][3]+=x3v*wq0.x;          \
    acc[ 1][0]+=x0v*wq0.y; acc[ 1][1]+=x1v*wq0.y; acc[ 1][2]+=x2v*wq0.y; acc[ 1][3]+=x3v*wq0.y;          \
    acc[ 2][0]+=x0v*wq0.z; acc[ 2][1]+=x1v*wq0.z; acc[ 2][2]+=x2v*wq0.z; acc[ 2][3]+=x3v*wq0.z;          \
    acc[ 3][0]+=x0v*wq0.w; acc[ 3][1]+=x1v*wq0.w; acc[ 3][2]+=x2v*wq0.w; acc[ 3][3]+=x3v*wq0.w;          \
    acc[ 4][0]+=x0v*wq1.x; acc[ 4][1]+=x1v*wq1.x; acc[ 4][2]+=x2v*wq1.x; acc[ 4][3]+=x3v*wq1.x;          \
    acc[ 5][0]+=x0v*wq1.y; acc[ 5][1]+=x1v*wq1.y; acc[ 5][2]+=x2v*wq1.y; acc[ 5][3]+=x3v*wq1.y;          \
    acc[ 6][0]+=x0v*wq1.z; acc[ 6][1]+=x1v*wq1.z; acc[ 6][2]+=x2v*wq1.z; acc[ 6][3]+=x3v*wq1.z;          \
    acc[ 7][0]+=x0v*wq1.w; acc[ 7][1]+=x1v*wq1.w; acc[ 7][2]+=x2v*wq1.w; acc[ 7][3]+=x3v*wq1.w;          \
    acc[ 8][0]+=x0v*wq2.x; acc[ 8][1]+=x1v*wq2.x; acc[ 8][2]+=x2v*wq2.x; acc[ 8][3]+=x3v*wq2.x;          \
    acc[ 9][0]+=x0v*wq2.y; acc[ 9][1]+=x1v*wq2.y; acc[ 9][2]+=x2v*wq2.y; acc[ 9][3]+=x3v*wq2.y;          \
    acc[10][0]+=x0v*wq2.z; acc[10][1]+=x1v*wq2.z; acc[10][2]+=x2v*wq2.z; acc[10][3]+=x3v*wq2.z;          \
    acc[11][0]+=x0v*wq2.w; acc[11][1]+=x1v*wq2.w; acc[11][2]+=x2v*wq2.w; acc[11][3]+=x3v*wq2.w;          \
    acc[12][0]+=x0v*wq3.x; acc[12][1]+=x1v*wq3.x; acc[12][2]+=x2v*wq3.x; acc[12][3]+=x3v*wq3.x;          \
    acc[13][0]+=x0v*wq3.y; acc[13][1]+=x1v*wq3.y; acc[13][2]+=x2v*wq3.y; acc[13][3]+=x3v*wq3.y;          \
    acc[14][0]+=x0v*wq3.z; acc[14][1]+=x1v*wq3.z; acc[14][2]+=x2v*wq3.z; acc[14][3]+=x3v*wq3.z;          \
    acc[15][0]+=x0v*wq3.w; acc[15][1]+=x1v*wq3.w; acc[15][2]+=x2v*wq3.w; acc[15][3]+=x3v*wq3.w;

// ---------------------------------------------------------------------------
// prep: zero stats, detect input dtype, compute sel
// ---------------------------------------------------------------------------
__global__ void k_prep(const void* __restrict__ x, const void* __restrict__ aw) {
    __shared__ int flag_s;
    __shared__ float red[256];
    const int t = threadIdx.x;
    for (int i = t; i < 8 * 512; i += 256) g_stats[i] = 0.f;
    const unsigned short* xu = (const unsigned short*)x;
    int bad = 0;
    for (int i = t; i < 8192; i += 256) {
        unsigned int e = (xu[i] >> 7) & 0xFFu;
        if (e >= 0xC6u) ++bad;
    }
    red[t] = (float)bad;
    __syncthreads();
    for (int off = 128; off > 0; off >>= 1) {
        if (t < off) red[t] += red[t + off];
        __syncthreads();
    }
    if (t == 0) { flag_s = (red[0] > 4.0f) ? 1 : 0; g_isf32 = flag_s; }
    __syncthreads();
    const int isf32 = flag_s;
    if (t == 0) {
        float w[8];
        float mx = -1e30f;
        for (int i = 0; i < 8; ++i) { w[i] = ldq(aw, i, isf32); mx = fmaxf(mx, w[i]); }
        float s = 0.f;
        for (int i = 0; i < 8; ++i) { w[i] = expf(w[i] - mx); s += w[i]; }
        for (int i = 0; i < 8; ++i) w[i] /= s;
        float sv[8] = {0,0,0,0,0,0,0,0};
        bool used[8] = {false,false,false,false,false,false,false,false};
        for (int k = 0; k < 3; ++k) {          // top-3, first-index tie-break
            int bi = -1; float bv = -1.f;
            for (int i = 0; i < 8; ++i) if (!used[i] && w[i] > bv) { bv = w[i]; bi = i; }
            used[bi] = true; sv[bi] = bv;
        }
        float tot = 0.f;
        for (int i = 0; i < 8; ++i) { if (sv[i] < 0.01f) sv[i] = 0.f; tot += sv[i]; }
        tot = fmaxf(tot, 1e-12f);
        for (int i = 0; i < 8; ++i) g_sel[i] = sv[i] / tot;
    }
}

// ---------------------------------------------------------------------------
// weight prepass: convert to f32, repack co-fastest (4x float4 per (ci,tap)).
// grid = 16 blocks (cg). Runs after k_prep (needs g_isf32).
// ---------------------------------------------------------------------------
__global__ __launch_bounds__(256)
void k_wconv(const void* __restrict__ w3, const void* __restrict__ w5,
             const void* __restrict__ wd, const void* __restrict__ wi,
             const void* __restrict__ wp) {
    const int cg = blockIdx.x;          // 0..15
    const int t  = threadIdx.x;
    const int isf32 = g_isf32;
    // w5: out o = ((ci*25+tap)*16+u)
    for (int o = t; o < 102400; o += 256) {
        int u = o & 15, r = o >> 4, tap = r % 25, ci = r / 25;
        g_w5f[(size_t)cg * 102400 + o] =
            ldq(w5, ((long)(cg * 16 + u) * C_ + ci) * 25 + tap, isf32);
    }
    // w3 / wd: out o = ((ci*9+tap)*16+u)
    for (int o = t; o < 36864; o += 256) {
        int u = o & 15, r = o >> 4, tap = r % 9, ci = r / 9;
        long ii = ((long)(cg * 16 + u) * C_ + ci) * 9 + tap;
        g_w3f[(size_t)cg * 36864 + o] = ldq(w3, ii, isf32);
        g_wdf[(size_t)cg * 36864 + o] = ldq(wd, ii, isf32);
    }
    // transition weights: [cg][ci=128][u=16]
    for (int o = t; o < 2048; o += 256) {
        int u = o & 15, ci = o >> 4;
        g_wtf[cg * 2048 + o] = ldq(wi, (long)(cg * 16 + u) * CIN_ + ci, isf32);
    }
    // pointwise weights: [cg][ci=256][u=16]
    for (int o = t; o < 4096; o += 256) {
        int u = o & 15, ci = o >> 4;
        g_wpf[cg * 4096 + o] = ldq(wp, (long)(cg * 16 + u) * C_ + ci, isf32);
    }
}

// ---------------------------------------------------------------------------
// stats epilogues
// ---------------------------------------------------------------------------
__device__ __forceinline__ void stats_epilogue(float* red, float s, float s2,
                                               int t, int c, int slot) {
    __syncthreads();
    red[t] = s; red[t + 256] = s2;
    __syncthreads();
    for (int off = 128; off > 0; off >>= 1) {
        if (t < off) { red[t] += red[t + off]; red[t + 256] += red[t + 256 + off]; }
        __syncthreads();
    }
    if (t == 0) {
        atomicAdd(&g_stats[slot * 512 + c], red[0]);
        atomicAdd(&g_stats[slot * 512 + 256 + c], red[256]);
    }
}

__device__ __forceinline__ void stats_ep2(float* red, int t,
                                          float sA, float s2A, float sB, float s2B,
                                          int cA, int cB, int slot) {
    __syncthreads();
    red[t] = sA; red[t + 256] = s2A; red[t + 512] = sB; red[t + 768] = s2B;
    __syncthreads();
    for (int off = 128; off > 0; off >>= 1) {
        if (t < off) {
            red[t]       += red[t + off];
            red[t + 256] += red[t + 256 + off];
            red[t + 512] += red[t + 512 + off];
            red[t + 768] += red[t + 768 + off];
        }
        __syncthreads();
    }
    if (t == 0) {
        atomicAdd(&g_stats[slot * 512 + cA],       red[0]);
        atomicAdd(&g_stats[slot * 512 + 256 + cA], red[256]);
        atomicAdd(&g_stats[slot * 512 + cB],       red[512]);
        atomicAdd(&g_stats[slot * 512 + 256 + cB], red[768]);
    }
}

__device__ __forceinline__ void stats_all16(float* red, int t, float acc[16][4],
                                            int c0, int slot) {
    #pragma unroll
    for (int u = 0; u < 16; u += 2)
        stats_ep2(red, t,
            acc[u][0]+acc[u][1]+acc[u][2]+acc[u][3],
            acc[u][0]*acc[u][0]+acc[u][1]*acc[u][1]+acc[u][2]*acc[u][2]+acc[u][3]*acc[u][3],
            acc[u+1][0]+acc[u+1][1]+acc[u+1][2]+acc[u+1][3],
            acc[u+1][0]*acc[u+1][0]+acc[u+1][1]*acc[u+1][1]+acc[u+1][2]*acc[u+1][2]+acc[u+1][3]*acc[u+1][3],
            c0 + u, c0 + u + 1, slot);
}

// ---------------------------------------------------------------------------
// transition 1x1 conv, COUT=16, NO LDS (direct strided coalesced loads)
// -> g_dw, stats slot 0. grid = 64 b * 16 cgroups = 1024
// __launch_bounds__(256,2): 2 blocks/CU -> VGPR cap 256 (acc[16][4] stays in regs)
// ---------------------------------------------------------------------------
__global__ __launch_bounds__(256, 2)
void k_trans(const void* __restrict__ xin) {
    __shared__ float red[1024];
    const int t  = threadIdx.x;
    const int cg = blockIdx.x & 15;
    const int c0 = cg * 16;
    const int b  = blockIdx.x >> 4;
    const float* wb = g_wtf + cg * 2048;
    float acc[16][4];
    #pragma unroll
    for (int k = 0; k < 16; ++k)
        #pragma unroll
        for (int j = 0; j < 4; ++j) acc[k][j] = 0.f;

    const size_t base0 = (size_t)b * CIN_ * 1024 + t;
    if (g_isf32) {
        const float* xf = (const float*)xin;
        for (int ci = 0; ci < CIN_; ++ci) {
            const float* xp = xf + base0 + (size_t)ci * 1024;
            float x0v = xp[0], x1v = xp[256], x2v = xp[512], x3v = xp[768];
            float4 wq0 = *(const float4*)(wb + ci * 16);
            float4 wq1 = *(const float4*)(wb + ci * 16 + 4);
            float4 wq2 = *(const float4*)(wb + ci * 16 + 8);
            float4 wq3 = *(const float4*)(wb + ci * 16 + 12);
            FMA16X4(acc, wq0, wq1, wq2, wq3, x0v, x1v, x2v, x3v)
        }
    } else {
        const unsigned short* xu = (const unsigned short*)xin;
        for (int ci = 0; ci < CIN_; ++ci) {
            const unsigned short* xp = xu + base0 + (size_t)ci * 1024;
            float x0v = u2f(xp[0]),   x1v = u2f(xp[256]);
            float x2v = u2f(xp[512]), x3v = u2f(xp[768]);
            float4 wq0 = *(const float4*)(wb + ci * 16);
            float4 wq1 = *(const float4*)(wb + ci * 16 + 4);
            float4 wq2 = *(const float4*)(wb + ci * 16 + 8);
            float4 wq3 = *(const float4*)(wb + ci * 16 + 12);
            FMA16X4(acc, wq0, wq1, wq2, wq3, x0v, x1v, x2v, x3v)
        }
    }
    #pragma unroll
    for (int k = 0; k < 16; ++k) {
        float* o = g_dw + (size_t)(b * C_ + c0 + k) * HW_;
        o[t] = acc[k][0]; o[t + 256] = acc[k][1];
        o[t + 512] = acc[k][2]; o[t + 768] = acc[k][3];
    }
    stats_all16(red, t, acc, c0, 0);
}

// ---------------------------------------------------------------------------
// FUSED post-transition pass (one per (b,c) channel):
//   h = relu(BN0(g_dw)) -> g_h ; stage h in LDS once;
//   pools (slots 1,2) -> g_pm/g_pa ; depthwise (op 6 part 1) -> g_dw in place.
// ---------------------------------------------------------------------------
__global__ __launch_bounds__(256)
void k_post(const void* __restrict__ g, const void* __restrict__ bb,
            const void* __restrict__ wdw) {
    __shared__ float xs[34 * 33];
    __shared__ float red[512];
    const int t = threadIdx.x;
    const int c = blockIdx.x & (C_ - 1);
    const int y  = t >> 3;
    const int x0 = (t & 7) * 4;
    const int isf32 = g_isf32;

    // BN0 + ReLU
    float mean = g_stats[c] * (1.0f / NPC_);
    float var  = g_stats[256 + c] * (1.0f / NPC_) - mean * mean;
    float rstd = rsqrtf(fmaxf(var, 0.f) + 1e-5f);
    float gv = ldq(g, c, isf32), bv = ldq(bb, c, isf32);
    float4 r = *(const float4*)(g_dw + (size_t)blockIdx.x * HW_ + t * 4);
    float4 h;
    h.x = fmaxf(0.f, (r.x - mean) * rstd * gv + bv);
    h.y = fmaxf(0.f, (r.y - mean) * rstd * gv + bv);
    h.z = fmaxf(0.f, (r.z - mean) * rstd * gv + bv);
    h.w = fmaxf(0.f, (r.w - mean) * rstd * gv + bv);
    *(float4*)(g_h + (size_t)blockIdx.x * HW_ + t * 4) = h;

    // stage h tile (stride-33)
    float* xw = xs + y * 33 + x0;
    xw[0] = h.x; xw[1] = h.y; xw[2] = h.z; xw[3] = h.w;
    __syncthreads();

    const float s1 = g_sel[1], s2 = g_sel[2], s6 = g_sel[6];

    if (s1 != 0.f || s2 != 0.f) {
        float mx[4] = {0.f, 0.f, 0.f, 0.f};   // h >= 0: matches padded max
        float sm[4] = {0.f, 0.f, 0.f, 0.f};
        #pragma unroll
        for (int ky = 0; ky < 3; ++ky) {
            int iy = y + ky - 1;
            if (iy < 0 || iy >= 32) continue;
            float row[6];
            #pragma unroll
            for (int i = 0; i < 6; ++i) {
                int ix = x0 + i - 1;
                row[i] = (ix >= 0 && ix < 32) ? xs[iy * 33 + ix] : 0.0f;
            }
            #pragma unroll
            for (int kx = 0; kx < 3; ++kx)
                #pragma unroll
                for (int j = 0; j < 4; ++j) {
                    mx[j] = fmaxf(mx[j], row[j + kx]);
                    sm[j] += row[j + kx];
                }
        }
        #pragma unroll
        for (int j = 0; j < 4; ++j) sm[j] *= (1.0f / 9.0f);
        const size_t ob = (size_t)blockIdx.x * HW_ + y * 32 + x0;
        if (s1 != 0.f) {
            float* o = g_pm + ob;
            o[0] = mx[0]; o[1] = mx[1]; o[2] = mx[2]; o[3] = mx[3];
            stats_epilogue(red, mx[0]+mx[1]+mx[2]+mx[3],
                           mx[0]*mx[0]+mx[1]*mx[1]+mx[2]*mx[2]+mx[3]*mx[3], t, c, 1);
        }
        if (s2 != 0.f) {
            float* o = g_pa + ob;
            o[0] = sm[0]; o[1] = sm[1]; o[2] = sm[2]; o[3] = sm[3];
            stats_epilogue(red, sm[0]+sm[1]+sm[2]+sm[3],
                           sm[0]*sm[0]+sm[1]*sm[1]+sm[2]*sm[2]+sm[3]*sm[3], t, c, 2);
        }
    }

    if (s6 != 0.f) {
        float wv[9];
        #pragma unroll
        for (int k = 0; k < 9; ++k) wv[k] = ldq(wdw, (long)c * 9 + k, isf32);
        float acc[4] = {0.f, 0.f, 0.f, 0.f};
        #pragma unroll
        for (int ky = 0; ky < 3; ++ky) {
            int iy = y + ky - 1;
            if (iy < 0 || iy >= 32) continue;
            float row[6];
            #pragma unroll
            for (int i = 0; i < 6; ++i) {
                int ix = x0 + i - 1;
                row[i] = (ix >= 0 && ix < 32) ? xs[iy * 33 + ix] : 0.0f;
            }
            #pragma unroll
            for (int kx = 0; kx < 3; ++kx)
                #pragma unroll
                for (int j = 0; j < 4; ++j)
                    acc[j] += row[j + kx] * wv[ky * 3 + kx];
        }
        float* o = g_dw + (size_t)blockIdx.x * HW_ + y * 32 + x0;
        o[0] = acc[0]; o[1] = acc[1]; o[2] = acc[2]; o[3] = acc[3];
    }
}

// ---------------------------------------------------------------------------
// SPECIALIZED dense conv, COUT=16, WAVE-PRIVATE zero-padded LDS tiles,
// zero barriers in the main loop (waves decoupled; per-wave dbuf).
// grid = 64 b * 16 cg = 1024. Per ci per thread (KS=3): 576 FMA inst.
// __launch_bounds__(256,2): 2 blocks/CU -> VGPR cap 256; acc[16][4] in regs
// (R7 post-mortem: default bound forced ~64-VGPR target -> scratch spill).
// ---------------------------------------------------------------------------
template<int KS, int DIL, int PAD, int SLOT>
__global__ __launch_bounds__(256, 2)
void k_conv1() {
    if (g_sel[SLOT] == 0.0f) return;
    constexpr int TRW  = 8 + 2 * PAD;       // wave tile rows (incl. halo)
    constexpr int TAPS = KS * KS;
    __shared__ float xs[4][2][TRW * 40];
    const int t  = threadIdx.x;
    const int w  = t >> 6;                   // wave 0..3
    const int l  = t & 63;
    const int cg = blockIdx.x & 15;
    const int c0 = cg * 16;
    const int b  = blockIdx.x >> 4;
    const int y  = l >> 3;                   // wave-local row 0..7
    const int x0 = (l & 7) * 4;
    const int y0 = w * 8;                    // wave's first output row
    const float* hb = g_h + (size_t)b * C_ * HW_;
    const float* wb = (SLOT == 4 ? g_w3f : SLOT == 5 ? g_w5f : g_wdf)
                      + (size_t)cg * (C_ * TAPS * 16);
    float* obuf = (SLOT == 4) ? g_c3 : (SLOT == 5) ? g_c5 : g_cd;

    // each lane stages tile row y (always) and tile row y+8 (if y < 2*PAD)
    const int grA = y0 - PAD + y;            // global row of tile row y
    const bool okA = (grA >= 0) && (grA < 32);
    const int grB = grA + 8;                 // global row of tile row y+8
    const bool okB = (y < 2 * PAD) && (grB < 32);

    float acc[16][4];
    #pragma unroll
    for (int u = 0; u < 16; ++u)
        #pragma unroll
        for (int j = 0; j < 4; ++j) acc[u][j] = 0.f;

    // zero wave-private double buffer (halo/pad stays zero forever)
    {
        float* xw = &xs[w][0][0];
        for (int i = l; i < 2 * TRW * 40; i += 64) xw[i] = 0.f;
    }
    // prologue: stage ci=0 (same-wave LDS ordering; no barrier needed)
    if (okA) *(float4*)(&xs[w][0][y * 40 + 4 + x0]) =
        *(const float4*)(hb + (size_t)grA * 32 + x0);
    if (okB) *(float4*)(&xs[w][0][(y + 8) * 40 + 4 + x0]) =
        *(const float4*)(hb + (size_t)grB * 32 + x0);
    int cur = 0;

    for (int ci = 0; ci < C_; ++ci) {
        // issue next-channel loads EARLY (hide under FMA body)
        float4 rA = {0.f,0.f,0.f,0.f}, rB = {0.f,0.f,0.f,0.f};
        if (ci + 1 < C_) {
            const float* hn = hb + (size_t)(ci + 1) * HW_;
            if (okA) rA = *(const float4*)(hn + grA * 32 + x0);
            if (okB) rB = *(const float4*)(hn + grB * 32 + x0);
        }
        const float* xsc = xs[w][cur];
        const float* wc  = wb + ci * (TAPS * 16);
        #pragma unroll
        for (int ky = 0; ky < KS; ++ky) {
            const int rr = (y + ky * DIL) * 40 + x0;
            // minimal aligned window reads from the zero-padded tile
            float wnd[12];
            if (PAD == 1) {                 // tile cols x0+3..x0+8
                wnd[3] = xsc[rr + 3];
                float4 qb = *(const float4*)(xsc + rr + 4);
                wnd[4] = qb.x; wnd[5] = qb.y; wnd[6] = qb.z; wnd[7] = qb.w;
                wnd[8] = xsc[rr + 8];
            } else {                        // tile cols x0+2..x0+9
                float2 qa = *(const float2*)(xsc + rr + 2);
                float4 qb = *(const float4*)(xsc + rr + 4);
                float2 qc = *(const float2*)(xsc + rr + 8);
                wnd[2] = qa.x; wnd[3] = qa.y;
                wnd[4] = qb.x; wnd[5] = qb.y; wnd[6] = qb.z; wnd[7] = qb.w;
                wnd[8] = qc.x; wnd[9] = qc.y;
            }
            #pragma unroll
            for (int kx = 0; kx < KS; ++kx) {
                const float4 wA = *(const float4*)(wc + (ky * KS + kx) * 16);
                const float4 wB = *(const float4*)(wc + (ky * KS + kx) * 16 + 4);
                const float4 wC = *(const float4*)(wc + (ky * KS + kx) * 16 + 8);
                const float4 wD = *(const float4*)(wc + (ky * KS + kx) * 16 + 12);
                #pragma unroll
                for (int j = 0; j < 4; ++j) {
                    const float v = wnd[(4 - PAD) + j + kx * DIL];
                    acc[ 0][j] += v * wA.x; acc[ 1][j] += v * wA.y;
                    acc[ 2][j] += v * wA.z; acc[ 3][j] += v * wA.w;
                    acc[ 4][j] += v * wB.x; acc[ 5][j] += v * wB.y;
                    acc[ 6][j] += v * wB.z; acc[ 7][j] += v * wB.w;
                    acc[ 8][j] += v * wC.x; acc[ 9][j] += v * wC.y;
                    acc[10][j] += v * wC.z; acc[11][j] += v * wC.w;
                    acc[12][j] += v * wD.x; acc[13][j] += v * wD.y;
                    acc[14][j] += v * wD.z; acc[15][j] += v * wD.w;
                }
            }
        }
        // write-late into the other wave-private buffer (no barrier)
        if (ci + 1 < C_) {
            float* xn = xs[w][cur ^ 1];
            if (okA) *(float4*)(xn + y * 40 + 4 + x0) = rA;
            if (okB) *(float4*)(xn + (y + 8) * 40 + 4 + x0) = rB;
        }
        cur ^= 1;
    }

    #pragma unroll
    for (int u = 0; u < 16; ++u) {
        float4 o; o.x = acc[u][0]; o.y = acc[u][1]; o.z = acc[u][2]; o.w = acc[u][3];
        *(float4*)(obuf + (size_t)(b * C_ + c0 + u) * HW_ + (y0 + y) * 32 + x0) = o;
    }
    // stats: alias red onto xs (safe: stats_ep2 starts with __syncthreads,
    // so every wave's LDS reads are complete before any red write)
    float* red = &xs[0][0][0];
    stats_all16(red, t, acc, c0, SLOT);
}

// ---------------------------------------------------------------------------
// pointwise 1x1 conv on g_dw, COUT=16, NO LDS -> g_pw + fused stats slot 6
// grid = 64 b * 16 cg = 1024. __launch_bounds__(256,2): no spill.
// ---------------------------------------------------------------------------
__global__ __launch_bounds__(256, 2)
void k_pw() {
    if (g_sel[6] == 0.0f) return;
    __shared__ float red[1024];
    const int t  = threadIdx.x;
    const int cg = blockIdx.x & 15;
    const int c0 = cg * 16;
    const int b  = blockIdx.x >> 4;
    const float* hb = g_dw + (size_t)b * C_ * HW_ + t;
    const float* wb = g_wpf + cg * 4096;
    float acc[16][4];
    #pragma unroll
    for (int k = 0; k < 16; ++k)
        #pragma unroll
        for (int j = 0; j < 4; ++j) acc[k][j] = 0.f;
    for (int ci = 0; ci < C_; ++ci) {
        const float* hp = hb + (size_t)ci * HW_;
        float x0v = hp[0], x1v = hp[256], x2v = hp[512], x3v = hp[768];
        float4 wq0 = *(const float4*)(wb + ci * 16);
        float4 wq1 = *(const float4*)(wb + ci * 16 + 4);
        float4 wq2 = *(const float4*)(wb + ci * 16 + 8);
        float4 wq3 = *(const float4*)(wb + ci * 16 + 12);
        FMA16X4(acc, wq0, wq1, wq2, wq3, x0v, x1v, x2v, x3v)
    }
    #pragma unroll
    for (int k = 0; k < 16; ++k) {
        float* o = g_pw + (size_t)(b * C_ + c0 + k) * HW_;
        o[t] = acc[k][0]; o[t + 256] = acc[k][1];
        o[t + 512] = acc[k][2]; o[t + 768] = acc[k][3];
    }
    stats_all16(red, t, acc, c0, 6);
}

// ---------------------------------------------------------------------------
// single fused epilogue: out = sel3*h + Σ sel_k * BN_k(buf_k), dtype-dual
// ---------------------------------------------------------------------------
__device__ __forceinline__ void bn_term(float4& o, const float* buf, size_t idx,
                                        int c, int slot, float sv,
                                        const void* g, const void* bb, int isf32) {
    float mean = g_stats[slot * 512 + c] * (1.0f / NPC_);
    float var  = g_stats[slot * 512 + 256 + c] * (1.0f / NPC_) - mean * mean;
    float rstd = rsqrtf(fmaxf(var, 0.f) + 1e-5f);
    float gv = ldq(g, c, isf32), bv = ldq(bb, c, isf32);
    float4 r = *(const float4*)(buf + idx);
    o.x += sv * ((r.x - mean) * rstd * gv + bv);
    o.y += sv * ((r.y - mean) * rstd * gv + bv);
    o.z += sv * ((r.z - mean) * rstd * gv + bv);
    o.w += sv * ((r.w - mean) * rstd * gv + bv);
}

__global__ __launch_bounds__(256)
void k_final_all(void* __restrict__ out,
                 const void* __restrict__ gmp, const void* __restrict__ bmp,
                 const void* __restrict__ gap, const void* __restrict__ bap,
                 const void* __restrict__ g3,  const void* __restrict__ b3,
                 const void* __restrict__ g5,  const void* __restrict__ b5,
                 const void* __restrict__ gs,  const void* __restrict__ bs,
                 const void* __restrict__ gd,  const void* __restrict__ bd) {
    size_t idx = ((size_t)blockIdx.x * 256 + threadIdx.x) * 4;
    int c = (int)((idx >> 10) & (C_ - 1));
    int isf32 = g_isf32;
    float4 o = {0.f, 0.f, 0.f, 0.f};
    float s3 = g_sel[3];
    if (s3 != 0.f) {
        float4 h = *(const float4*)(g_h + idx);
        o.x = s3 * h.x; o.y = s3 * h.y; o.z = s3 * h.z; o.w = s3 * h.w;
    }
    float sv;
    if ((sv = g_sel[1]) != 0.f) bn_term(o, g_pm, idx, c, 1, sv, gmp, bmp, isf32);
    if ((sv = g_sel[2]) != 0.f) bn_term(o, g_pa, idx, c, 2, sv, gap, bap, isf32);
    if ((sv = g_sel[4]) != 0.f) bn_term(o, g_c3, idx, c, 4, sv, g3,  b3,  isf32);
    if ((sv = g_sel[5]) != 0.f) bn_term(o, g_c5, idx, c, 5, sv, g5,  b5,  isf32);
    if ((sv = g_sel[6]) != 0.f) bn_term(o, g_pw, idx, c, 6, sv, gs,  bs,  isf32);
    if ((sv = g_sel[7]) != 0.f) bn_term(o, g_cd, idx, c, 7, sv, gd,  bd,  isf32);
    if (isf32) {
        *(float4*)((float*)out + idx) = o;
    } else {
        ushort4 u; u.x = f2u(o.x); u.y = f2u(o.y); u.z = f2u(o.z); u.w = f2u(o.w);
        *(ushort4*)((unsigned short*)out + idx) = u;
    }
}

// ---------------------------------------------------------------------------
extern "C" void kernel_launch(void* const* d_in, const int* in_sizes, int n_in,
                              void* d_out, int out_size, void* d_ws, size_t ws_size,
                              hipStream_t stream) {
    const void* x    = d_in[0];
    const void* aw   = d_in[1];
    const void* w_in = d_in[2];
    const void* g_in = d_in[3];
    const void* b_in = d_in[4];
    const void* w3   = d_in[5];
    const void* g3   = d_in[6];
    const void* b3   = d_in[7];
    const void* w5   = d_in[8];
    const void* g5   = d_in[9];
    const void* b5   = d_in[10];
    const void* wdw  = d_in[11];
    const void* wpw  = d_in[12];
    const void* gs   = d_in[13];
    const void* bs   = d_in[14];
    const void* wd   = d_in[15];
    const void* gd   = d_in[16];
    const void* bd   = d_in[17];
    const void* gmp  = d_in[18];
    const void* bmp  = d_in[19];
    const void* gap  = d_in[20];
    const void* bap  = d_in[21];

    dim3 Bk(256);
    dim3 Gfull(NB_);    // 16384 per-(b,c) blocks
    dim3 Gc16(1024);    // COUT=16 conv blocks (64 b * 16 cg)

    k_prep<<<dim3(1), Bk, 0, stream>>>(x, aw);
    k_wconv<<<dim3(16), Bk, 0, stream>>>(w3, w5, wd, w_in, wpw);

    // transition: 1x1 conv (COUT=16, no-LDS) -> g_dw
    k_trans<<<Gc16, Bk, 0, stream>>>(x);

    // fused: BN0+ReLU -> g_h ; pools -> g_pm/g_pa ; depthwise -> g_dw
    k_post<<<Gfull, Bk, 0, stream>>>(g_in, b_in, wdw);

    // ops 4/5/7: specialized dense convs, COUT=16, wave-private pipeline
    k_conv1<3, 1, 1, 4><<<Gc16, Bk, 0, stream>>>();   // conv3x3   -> g_c3
    k_conv1<5, 1, 2, 5><<<Gc16, Bk, 0, stream>>>();   // conv5x5   -> g_c5
    k_conv1<3, 2, 2, 7><<<Gc16, Bk, 0, stream>>>();   // dil conv  -> g_cd

    // op 6 part 2: pointwise (COUT=16, no-LDS) -> g_pw
    k_pw<<<Gc16, Bk, 0, stream>>>();

    // single fused epilogue: out = sel3*h + sum sel_k*BN_k(buf_k)
    k_final_all<<<Gfull, Bk, 0, stream>>>(d_out,
        gmp, bmp, gap, bap, g3, b3, g5, b5, gs, bs, gd, bd);
}

// Round 10
// 1685.229 us; speedup vs baseline: 1.0409x; 1.0409x over previous
//
#include <hip/hip_runtime.h>

#define CIN_  128
#define C_    256
#define HW_   1024      /* 32*32 */
#define NPC_  65536.0f  /* 64*1024 elements per channel for BN stats */
#define NB_   16384     /* 64 batches * 256 channels */

constexpr size_t NELEM = 16777216ull;   // 64*256*32*32

// ---- module-scope device scratch: one buffer per producer (no reuse hazards)
__device__ float g_sel[8];
__device__ float g_stats[8 * 512];      // per-slot: [0..255]=sum, [256..511]=sumsq
__device__ int   g_isf32;
__device__ float g_h[NELEM];            // relu(BN0(trans))
__device__ float g_c3[NELEM];           // conv3x3 out      (slot 4)
__device__ float g_c5[NELEM];           // conv5x5 out      (slot 5)
__device__ float g_cd[NELEM];           // dil conv out     (slot 7)
__device__ float g_pm[NELEM];           // maxpool out      (slot 1)
__device__ float g_pa[NELEM];           // avgpool out      (slot 2)
__device__ float g_pw[NELEM];           // pointwise out    (slot 6)
__device__ float g_dw[NELEM];           // trans tmp, then depthwise out

// ---- prepass-converted f32 weights, packed co-fastest (16 per tap) ---------
// g_w5f: [cg=16][ci=256][tap=25][u=16]  (co = cg*16+u)
// g_w3f/g_wdf: [cg=16][ci=256][tap=9][u=16]
// g_wtf: [cg=16][ci=128][u=16]  g_wpf: [cg=16][ci=256][u=16]
__device__ float g_w5f[16 * 256 * 25 * 16];
__device__ float g_w3f[16 * 256 * 9 * 16];
__device__ float g_wdf[16 * 256 * 9 * 16];
__device__ float g_wtf[16 * 128 * 16];
__device__ float g_wpf[16 * 256 * 16];

__device__ __forceinline__ float u2f(unsigned short u) {
    union { unsigned int i; float f; } x; x.i = ((unsigned int)u) << 16; return x.f;
}
__device__ __forceinline__ unsigned short f2u(float f) {
    union { float f; unsigned int i; } x; x.f = f;
    unsigned int r = x.i + 0x7fffu + ((x.i >> 16) & 1u);  // RNE
    return (unsigned short)(r >> 16);
}
__device__ __forceinline__ float ldq(const void* p, long i, int isf32) {
    return isf32 ? ((const float*)p)[i] : u2f(((const unsigned short*)p)[i]);
}

// named-accumulator FMA helpers. NOTE: macro param is W (capital) — a
// lowercase `w` param would be substituted into the `.w` member access.
#define CF(A, W) A.x += vv.x*(W); A.y += vv.y*(W); A.z += vv.z*(W); A.w += vv.w*(W);
#define PF(A, W) A.x += x0v*(W); A.y += x1v*(W); A.z += x2v*(W); A.w += x3v*(W);
#define DECL16F4(c) \
    float4 c##00={0,0,0,0}, c##01={0,0,0,0}, c##02={0,0,0,0}, c##03={0,0,0,0}, \
           c##04={0,0,0,0}, c##05={0,0,0,0}, c##06={0,0,0,0}, c##07={0,0,0,0}, \
           c##08={0,0,0,0}, c##09={0,0,0,0}, c##10={0,0,0,0}, c##11={0,0,0,0}, \
           c##12={0,0,0,0}, c##13={0,0,0,0}, c##14={0,0,0,0}, c##15={0,0,0,0};

#define PF16BLOCK \
    PF(a00,wq0.x) PF(a01,wq0.y) PF(a02,wq0.z) PF(a03,wq0.w) \
    PF(a04,wq1.x) PF(a05,wq1.y) PF(a06,wq1.z) PF(a07,wq1.w) \
    PF(a08,wq2.x) PF(a09,wq2.y) PF(a10,wq2.z) PF(a11,wq2.w) \
    PF(a12,wq3.x) PF(a13,wq3.y) PF(a14,wq3.z) PF(a15,wq3.w)

#define STORE16(buf, A, k)                                                    \
    { float* o = (buf) + (size_t)(b * C_ + c0 + (k)) * HW_;                   \
      o[t] = A.x; o[t + 256] = A.y; o[t + 512] = A.z; o[t + 768] = A.w; }

// ---------------------------------------------------------------------------
// prep: zero stats, detect input dtype, compute sel
// ---------------------------------------------------------------------------
__global__ void k_prep(const void* __restrict__ x, const void* __restrict__ aw) {
    __shared__ int flag_s;
    __shared__ float red[256];
    const int t = threadIdx.x;
    for (int i = t; i < 8 * 512; i += 256) g_stats[i] = 0.f;
    const unsigned short* xu = (const unsigned short*)x;
    int bad = 0;
    for (int i = t; i < 8192; i += 256) {
        unsigned int e = (xu[i] >> 7) & 0xFFu;
        if (e >= 0xC6u) ++bad;
    }
    red[t] = (float)bad;
    __syncthreads();
    for (int off = 128; off > 0; off >>= 1) {
        if (t < off) red[t] += red[t + off];
        __syncthreads();
    }
    if (t == 0) { flag_s = (red[0] > 4.0f) ? 1 : 0; g_isf32 = flag_s; }
    __syncthreads();
    const int isf32 = flag_s;
    if (t == 0) {
        float w[8];
        float mx = -1e30f;
        for (int i = 0; i < 8; ++i) { w[i] = ldq(aw, i, isf32); mx = fmaxf(mx, w[i]); }
        float s = 0.f;
        for (int i = 0; i < 8; ++i) { w[i] = expf(w[i] - mx); s += w[i]; }
        for (int i = 0; i < 8; ++i) w[i] /= s;
        float sv[8] = {0,0,0,0,0,0,0,0};
        bool used[8] = {false,false,false,false,false,false,false,false};
        for (int k = 0; k < 3; ++k) {          // top-3, first-index tie-break
            int bi = -1; float bv = -1.f;
            for (int i = 0; i < 8; ++i) if (!used[i] && w[i] > bv) { bv = w[i]; bi = i; }
            used[bi] = true; sv[bi] = bv;
        }
        float tot = 0.f;
        for (int i = 0; i < 8; ++i) { if (sv[i] < 0.01f) sv[i] = 0.f; tot += sv[i]; }
        tot = fmaxf(tot, 1e-12f);
        for (int i = 0; i < 8; ++i) g_sel[i] = sv[i] / tot;
    }
}

// ---------------------------------------------------------------------------
// weight prepass: convert to f32, repack co-fastest (4x float4 per (ci,tap)).
// ---------------------------------------------------------------------------
__global__ __launch_bounds__(256)
void k_wconv(const void* __restrict__ w3, const void* __restrict__ w5,
             const void* __restrict__ wd, const void* __restrict__ wi,
             const void* __restrict__ wp) {
    const int cg = blockIdx.x;          // 0..15
    const int t  = threadIdx.x;
    const int isf32 = g_isf32;
    for (int o = t; o < 102400; o += 256) {
        int u = o & 15;
        int r = o >> 4;
        int tap = r % 25;
        int ci = r / 25;
        g_w5f[(size_t)cg * 102400 + o] =
            ldq(w5, ((long)(cg * 16 + u) * C_ + ci) * 25 + tap, isf32);
    }
    for (int o = t; o < 36864; o += 256) {
        int u = o & 15;
        int r = o >> 4;
        int tap = r % 9;
        int ci = r / 9;
        long ii = ((long)(cg * 16 + u) * C_ + ci) * 9 + tap;
        g_w3f[(size_t)cg * 36864 + o] = ldq(w3, ii, isf32);
        g_wdf[(size_t)cg * 36864 + o] = ldq(wd, ii, isf32);
    }
    for (int o = t; o < 2048; o += 256) {
        int u = o & 15;
        int ci = o >> 4;
        g_wtf[cg * 2048 + o] = ldq(wi, (long)(cg * 16 + u) * CIN_ + ci, isf32);
    }
    for (int o = t; o < 4096; o += 256) {
        int u = o & 15;
        int ci = o >> 4;
        g_wpf[cg * 4096 + o] = ldq(wp, (long)(cg * 16 + u) * C_ + ci, isf32);
    }
}

// ---------------------------------------------------------------------------
// stats epilogues
// ---------------------------------------------------------------------------
__device__ __forceinline__ void stats_epilogue(float* red, float s, float s2,
                                               int t, int c, int slot) {
    __syncthreads();
    red[t] = s; red[t + 256] = s2;
    __syncthreads();
    for (int off = 128; off > 0; off >>= 1) {
        if (t < off) { red[t] += red[t + off]; red[t + 256] += red[t + 256 + off]; }
        __syncthreads();
    }
    if (t == 0) {
        atomicAdd(&g_stats[slot * 512 + c], red[0]);
        atomicAdd(&g_stats[slot * 512 + 256 + c], red[256]);
    }
}

__device__ __forceinline__ void stats_ep2(float* red, int t,
                                          float sA, float s2A, float sB, float s2B,
                                          int cA, int cB, int slot) {
    __syncthreads();
    red[t] = sA; red[t + 256] = s2A; red[t + 512] = sB; red[t + 768] = s2B;
    __syncthreads();
    for (int off = 128; off > 0; off >>= 1) {
        if (t < off) {
            red[t]       += red[t + off];
            red[t + 256] += red[t + 256 + off];
            red[t + 512] += red[t + 512 + off];
            red[t + 768] += red[t + 768 + off];
        }
        __syncthreads();
    }
    if (t == 0) {
        atomicAdd(&g_stats[slot * 512 + cA],       red[0]);
        atomicAdd(&g_stats[slot * 512 + 256 + cA], red[256]);
        atomicAdd(&g_stats[slot * 512 + cB],       red[512]);
        atomicAdd(&g_stats[slot * 512 + 256 + cB], red[768]);
    }
}

// float4-pair variant (named accumulators, no array round-trip)
__device__ __forceinline__ void stats_ep2v(float* red, int t, float4 A, float4 B,
                                           int cA, int cB, int slot) {
    stats_ep2(red, t,
              A.x + A.y + A.z + A.w, A.x*A.x + A.y*A.y + A.z*A.z + A.w*A.w,
              B.x + B.y + B.z + B.w, B.x*B.x + B.y*B.y + B.z*B.z + B.w*B.w,
              cA, cB, slot);
}

#define STATS16V(red, t, c, c0, slot)                      \
    stats_ep2v(red, t, c##00, c##01, (c0) + 0,  (c0) + 1,  slot); \
    stats_ep2v(red, t, c##02, c##03, (c0) + 2,  (c0) + 3,  slot); \
    stats_ep2v(red, t, c##04, c##05, (c0) + 4,  (c0) + 5,  slot); \
    stats_ep2v(red, t, c##06, c##07, (c0) + 6,  (c0) + 7,  slot); \
    stats_ep2v(red, t, c##08, c##09, (c0) + 8,  (c0) + 9,  slot); \
    stats_ep2v(red, t, c##10, c##11, (c0) + 10, (c0) + 11, slot); \
    stats_ep2v(red, t, c##12, c##13, (c0) + 12, (c0) + 13, slot); \
    stats_ep2v(red, t, c##14, c##15, (c0) + 14, (c0) + 15, slot);

// ---------------------------------------------------------------------------
// transition 1x1 conv, COUT=16, NO LDS, named float4 accumulators.
// grid = 64 b * 16 cg = 1024. __launch_bounds__(256,4): 128-VGPR cap, no spill.
// ---------------------------------------------------------------------------
__global__ __launch_bounds__(256, 4)
void k_trans(const void* __restrict__ xin) {
    __shared__ float red[1024];
    const int t  = threadIdx.x;
    const int cg = blockIdx.x & 15;
    const int c0 = cg * 16;
    const int b  = blockIdx.x >> 4;
    const float* wb = g_wtf + cg * 2048;
    DECL16F4(a)
    const size_t base0 = (size_t)b * CIN_ * 1024 + t;
    if (g_isf32) {
        const float* xf = (const float*)xin;
        for (int ci = 0; ci < CIN_; ++ci) {
            const float* xp = xf + base0 + (size_t)ci * 1024;
            float x0v = xp[0];
            float x1v = xp[256];
            float x2v = xp[512];
            float x3v = xp[768];
            const float4 wq0 = *(const float4*)(wb + ci * 16);
            const float4 wq1 = *(const float4*)(wb + ci * 16 + 4);
            const float4 wq2 = *(const float4*)(wb + ci * 16 + 8);
            const float4 wq3 = *(const float4*)(wb + ci * 16 + 12);
            PF16BLOCK
        }
    } else {
        const unsigned short* xu = (const unsigned short*)xin;
        for (int ci = 0; ci < CIN_; ++ci) {
            const unsigned short* xp = xu + base0 + (size_t)ci * 1024;
            float x0v = u2f(xp[0]);
            float x1v = u2f(xp[256]);
            float x2v = u2f(xp[512]);
            float x3v = u2f(xp[768]);
            const float4 wq0 = *(const float4*)(wb + ci * 16);
            const float4 wq1 = *(const float4*)(wb + ci * 16 + 4);
            const float4 wq2 = *(const float4*)(wb + ci * 16 + 8);
            const float4 wq3 = *(const float4*)(wb + ci * 16 + 12);
            PF16BLOCK
        }
    }
    STORE16(g_dw, a00, 0)  STORE16(g_dw, a01, 1)  STORE16(g_dw, a02, 2)  STORE16(g_dw, a03, 3)
    STORE16(g_dw, a04, 4)  STORE16(g_dw, a05, 5)  STORE16(g_dw, a06, 6)  STORE16(g_dw, a07, 7)
    STORE16(g_dw, a08, 8)  STORE16(g_dw, a09, 9)  STORE16(g_dw, a10, 10) STORE16(g_dw, a11, 11)
    STORE16(g_dw, a12, 12) STORE16(g_dw, a13, 13) STORE16(g_dw, a14, 14) STORE16(g_dw, a15, 15)
    STATS16V(red, t, a, c0, 0)
}

// ---------------------------------------------------------------------------
// FUSED post-transition pass (one per (b,c) channel):
//   h = relu(BN0(g_dw)) -> g_h ; stage h in LDS once;
//   pools (slots 1,2) -> g_pm/g_pa ; depthwise (op 6 part 1) -> g_dw in place.
// ---------------------------------------------------------------------------
__global__ __launch_bounds__(256)
void k_post(const void* __restrict__ g, const void* __restrict__ bb,
            const void* __restrict__ wdw) {
    __shared__ float xs[34 * 33];
    __shared__ float red[512];
    const int t = threadIdx.x;
    const int c = blockIdx.x & (C_ - 1);
    const int y  = t >> 3;
    const int x0 = (t & 7) * 4;
    const int isf32 = g_isf32;

    float mean = g_stats[c] * (1.0f / NPC_);
    float var  = g_stats[256 + c] * (1.0f / NPC_) - mean * mean;
    float rstd = rsqrtf(fmaxf(var, 0.f) + 1e-5f);
    float gv = ldq(g, c, isf32), bv = ldq(bb, c, isf32);
    float4 r = *(const float4*)(g_dw + (size_t)blockIdx.x * HW_ + t * 4);
    float4 h;
    h.x = fmaxf(0.f, (r.x - mean) * rstd * gv + bv);
    h.y = fmaxf(0.f, (r.y - mean) * rstd * gv + bv);
    h.z = fmaxf(0.f, (r.z - mean) * rstd * gv + bv);
    h.w = fmaxf(0.f, (r.w - mean) * rstd * gv + bv);
    *(float4*)(g_h + (size_t)blockIdx.x * HW_ + t * 4) = h;

    float* xw = xs + y * 33 + x0;
    xw[0] = h.x; xw[1] = h.y; xw[2] = h.z; xw[3] = h.w;
    __syncthreads();

    const float s1 = g_sel[1], s2 = g_sel[2], s6 = g_sel[6];

    if (s1 != 0.f || s2 != 0.f) {
        float mx[4] = {0.f, 0.f, 0.f, 0.f};   // h >= 0: matches padded max
        float sm[4] = {0.f, 0.f, 0.f, 0.f};
        #pragma unroll
        for (int ky = 0; ky < 3; ++ky) {
            int iy = y + ky - 1;
            if (iy < 0 || iy >= 32) continue;
            float row[6];
            #pragma unroll
            for (int i = 0; i < 6; ++i) {
                int ix = x0 + i - 1;
                row[i] = (ix >= 0 && ix < 32) ? xs[iy * 33 + ix] : 0.0f;
            }
            #pragma unroll
            for (int kx = 0; kx < 3; ++kx)
                #pragma unroll
                for (int j = 0; j < 4; ++j) {
                    mx[j] = fmaxf(mx[j], row[j + kx]);
                    sm[j] += row[j + kx];
                }
        }
        #pragma unroll
        for (int j = 0; j < 4; ++j) sm[j] *= (1.0f / 9.0f);
        const size_t ob = (size_t)blockIdx.x * HW_ + y * 32 + x0;
        if (s1 != 0.f) {
            float* o = g_pm + ob;
            o[0] = mx[0]; o[1] = mx[1]; o[2] = mx[2]; o[3] = mx[3];
            stats_epilogue(red, mx[0]+mx[1]+mx[2]+mx[3],
                           mx[0]*mx[0]+mx[1]*mx[1]+mx[2]*mx[2]+mx[3]*mx[3], t, c, 1);
        }
        if (s2 != 0.f) {
            float* o = g_pa + ob;
            o[0] = sm[0]; o[1] = sm[1]; o[2] = sm[2]; o[3] = sm[3];
            stats_epilogue(red, sm[0]+sm[1]+sm[2]+sm[3],
                           sm[0]*sm[0]+sm[1]*sm[1]+sm[2]*sm[2]+sm[3]*sm[3], t, c, 2);
        }
    }

    if (s6 != 0.f) {
        float wv[9];
        #pragma unroll
        for (int k = 0; k < 9; ++k) wv[k] = ldq(wdw, (long)c * 9 + k, isf32);
        float acc[4] = {0.f, 0.f, 0.f, 0.f};
        #pragma unroll
        for (int ky = 0; ky < 3; ++ky) {
            int iy = y + ky - 1;
            if (iy < 0 || iy >= 32) continue;
            float row[6];
            #pragma unroll
            for (int i = 0; i < 6; ++i) {
                int ix = x0 + i - 1;
                row[i] = (ix >= 0 && ix < 32) ? xs[iy * 33 + ix] : 0.0f;
            }
            #pragma unroll
            for (int kx = 0; kx < 3; ++kx)
                #pragma unroll
                for (int j = 0; j < 4; ++j)
                    acc[j] += row[j + kx] * wv[ky * 3 + kx];
        }
        float* o = g_dw + (size_t)blockIdx.x * HW_ + y * 32 + x0;
        o[0] = acc[0]; o[1] = acc[1]; o[2] = acc[2]; o[3] = acc[3];
    }
}

// ---------------------------------------------------------------------------
// SPECIALIZED dense conv, COUT=16, named float4 accumulators, wave-private
// zero-padded LDS tiles, zero barriers in the main loop.
// grid = 64 b * 16 cg = 1024. __launch_bounds__(256,4): 128-VGPR cap,
// est. peak ~112 regs -> no spill, 4 waves/SIMD.
// ---------------------------------------------------------------------------
template<int KS, int DIL, int PAD, int SLOT>
__global__ __launch_bounds__(256, 4)
void k_conv1() {
    if (g_sel[SLOT] == 0.0f) return;
    constexpr int TRW  = 8 + 2 * PAD;       // wave tile rows (incl. halo)
    constexpr int TAPS = KS * KS;
    __shared__ float xs[4][2][TRW * 40];
    const int t  = threadIdx.x;
    const int w  = t >> 6;                   // wave 0..3
    const int l  = t & 63;
    const int cg = blockIdx.x & 15;
    const int c0 = cg * 16;
    const int b  = blockIdx.x >> 4;
    const int y  = l >> 3;                   // wave-local row 0..7
    const int x0 = (l & 7) * 4;
    const int y0 = w * 8;                    // wave's first output row
    const float* hb = g_h + (size_t)b * C_ * HW_;
    const float* wb = (SLOT == 4 ? g_w3f : SLOT == 5 ? g_w5f : g_wdf)
                      + (size_t)cg * (C_ * TAPS * 16);
    float* obuf = (SLOT == 4) ? g_c3 : (SLOT == 5) ? g_c5 : g_cd;

    const int grA = y0 - PAD + y;            // global row of tile row y
    const bool okA = (grA >= 0) && (grA < 32);
    const int grB = grA + 8;                 // global row of tile row y+8
    const bool okB = (y < 2 * PAD) && (grB < 32);

    DECL16F4(c)

    {   // zero wave-private double buffer (halo/pad stays zero forever)
        float* xw = &xs[w][0][0];
        for (int i = l; i < 2 * TRW * 40; i += 64) xw[i] = 0.f;
    }
    // prologue: stage ci=0 (same-wave LDS ordering; no barrier needed)
    if (okA) *(float4*)(&xs[w][0][y * 40 + 4 + x0]) =
        *(const float4*)(hb + (size_t)grA * 32 + x0);
    if (okB) *(float4*)(&xs[w][0][(y + 8) * 40 + 4 + x0]) =
        *(const float4*)(hb + (size_t)grB * 32 + x0);
    int cur = 0;

    for (int ci = 0; ci < C_; ++ci) {
        // issue next-channel loads EARLY (hide under FMA body)
        float4 rA = {0.f,0.f,0.f,0.f};
        float4 rB = {0.f,0.f,0.f,0.f};
        if (ci + 1 < C_) {
            const float* hn = hb + (size_t)(ci + 1) * HW_;
            if (okA) rA = *(const float4*)(hn + grA * 32 + x0);
            if (okB) rB = *(const float4*)(hn + grB * 32 + x0);
        }
        const float* xsc = xs[w][cur];
        const float* wc  = wb + ci * (TAPS * 16);
        #pragma unroll
        for (int ky = 0; ky < KS; ++ky) {
            const int rr = (y + ky * DIL) * 40 + x0;
            // minimal aligned window reads from the zero-padded tile
            float wnd[12];
            if (PAD == 1) {                 // tile cols x0+3..x0+8
                wnd[3] = xsc[rr + 3];
                float4 qb = *(const float4*)(xsc + rr + 4);
                wnd[4] = qb.x; wnd[5] = qb.y; wnd[6] = qb.z; wnd[7] = qb.w;
                wnd[8] = xsc[rr + 8];
            } else {                        // tile cols x0+2..x0+9
                float2 qa = *(const float2*)(xsc + rr + 2);
                float4 qb = *(const float4*)(xsc + rr + 4);
                float2 qc = *(const float2*)(xsc + rr + 8);
                wnd[2] = qa.x; wnd[3] = qa.y;
                wnd[4] = qb.x; wnd[5] = qb.y; wnd[6] = qb.z; wnd[7] = qb.w;
                wnd[8] = qc.x; wnd[9] = qc.y;
            }
            #pragma unroll
            for (int kx = 0; kx < KS; ++kx) {
                const float4 wA = *(const float4*)(wc + (ky * KS + kx) * 16);
                const float4 wB = *(const float4*)(wc + (ky * KS + kx) * 16 + 4);
                const float4 wC = *(const float4*)(wc + (ky * KS + kx) * 16 + 8);
                const float4 wD = *(const float4*)(wc + (ky * KS + kx) * 16 + 12);
                float4 vv;
                vv.x = wnd[(4 - PAD) + 0 + kx * DIL];
                vv.y = wnd[(4 - PAD) + 1 + kx * DIL];
                vv.z = wnd[(4 - PAD) + 2 + kx * DIL];
                vv.w = wnd[(4 - PAD) + 3 + kx * DIL];
                CF(c00, wA.x) CF(c01, wA.y) CF(c02, wA.z) CF(c03, wA.w)
                CF(c04, wB.x) CF(c05, wB.y) CF(c06, wB.z) CF(c07, wB.w)
                CF(c08, wC.x) CF(c09, wC.y) CF(c10, wC.z) CF(c11, wC.w)
                CF(c12, wD.x) CF(c13, wD.y) CF(c14, wD.z) CF(c15, wD.w)
            }
        }
        // write-late into the other wave-private buffer (no barrier)
        if (ci + 1 < C_) {
            float* xn = xs[w][cur ^ 1];
            if (okA) *(float4*)(xn + y * 40 + 4 + x0) = rA;
            if (okB) *(float4*)(xn + (y + 8) * 40 + 4 + x0) = rB;
        }
        cur ^= 1;
    }

    const size_t obase = (size_t)(b * C_ + c0) * HW_ + (y0 + y) * 32 + x0;
    #define CSTORE(A, u) *(float4*)(obuf + obase + (size_t)(u) * HW_) = A;
    CSTORE(c00, 0)  CSTORE(c01, 1)  CSTORE(c02, 2)  CSTORE(c03, 3)
    CSTORE(c04, 4)  CSTORE(c05, 5)  CSTORE(c06, 6)  CSTORE(c07, 7)
    CSTORE(c08, 8)  CSTORE(c09, 9)  CSTORE(c10, 10) CSTORE(c11, 11)
    CSTORE(c12, 12) CSTORE(c13, 13) CSTORE(c14, 14) CSTORE(c15, 15)
    #undef CSTORE
    // stats: alias red onto xs (safe: stats_ep2 starts with __syncthreads,
    // so every wave's LDS reads are complete before any red write)
    float* red = &xs[0][0][0];
    STATS16V(red, t, c, c0, SLOT)
}

// ---------------------------------------------------------------------------
// pointwise 1x1 conv on g_dw, COUT=16, NO LDS, named float4 accumulators
// -> g_pw + fused stats slot 6. grid = 1024. __launch_bounds__(256,4).
// ---------------------------------------------------------------------------
__global__ __launch_bounds__(256, 4)
void k_pw() {
    if (g_sel[6] == 0.0f) return;
    __shared__ float red[1024];
    const int t  = threadIdx.x;
    const int cg = blockIdx.x & 15;
    const int c0 = cg * 16;
    const int b  = blockIdx.x >> 4;
    const float* hb = g_dw + (size_t)b * C_ * HW_ + t;
    const float* wb = g_wpf + cg * 4096;
    DECL16F4(a)
    for (int ci = 0; ci < C_; ++ci) {
        const float* hp = hb + (size_t)ci * HW_;
        float x0v = hp[0];
        float x1v = hp[256];
        float x2v = hp[512];
        float x3v = hp[768];
        const float4 wq0 = *(const float4*)(wb + ci * 16);
        const float4 wq1 = *(const float4*)(wb + ci * 16 + 4);
        const float4 wq2 = *(const float4*)(wb + ci * 16 + 8);
        const float4 wq3 = *(const float4*)(wb + ci * 16 + 12);
        PF16BLOCK
    }
    STORE16(g_pw, a00, 0)  STORE16(g_pw, a01, 1)  STORE16(g_pw, a02, 2)  STORE16(g_pw, a03, 3)
    STORE16(g_pw, a04, 4)  STORE16(g_pw, a05, 5)  STORE16(g_pw, a06, 6)  STORE16(g_pw, a07, 7)
    STORE16(g_pw, a08, 8)  STORE16(g_pw, a09, 9)  STORE16(g_pw, a10, 10) STORE16(g_pw, a11, 11)
    STORE16(g_pw, a12, 12) STORE16(g_pw, a13, 13) STORE16(g_pw, a14, 14) STORE16(g_pw, a15, 15)
    STATS16V(red, t, a, c0, 6)
}

// ---------------------------------------------------------------------------
// single fused epilogue: out = sel3*h + Σ sel_k * BN_k(buf_k), dtype-dual
// ---------------------------------------------------------------------------
__device__ __forceinline__ void bn_term(float4& o, const float* buf, size_t idx,
                                        int c, int slot, float sv,
                                        const void* g, const void* bb, int isf32) {
    float mean = g_stats[slot * 512 + c] * (1.0f / NPC_);
    float var  = g_stats[slot * 512 + 256 + c] * (1.0f / NPC_) - mean * mean;
    float rstd = rsqrtf(fmaxf(var, 0.f) + 1e-5f);
    float gv = ldq(g, c, isf32), bv = ldq(bb, c, isf32);
    float4 r = *(const float4*)(buf + idx);
    o.x += sv * ((r.x - mean) * rstd * gv + bv);
    o.y += sv * ((r.y - mean) * rstd * gv + bv);
    o.z += sv * ((r.z - mean) * rstd * gv + bv);
    o.w += sv * ((r.w - mean) * rstd * gv + bv);
}

__global__ __launch_bounds__(256)
void k_final_all(void* __restrict__ out,
                 const void* __restrict__ gmp, const void* __restrict__ bmp,
                 const void* __restrict__ gap, const void* __restrict__ bap,
                 const void* __restrict__ g3,  const void* __restrict__ b3,
                 const void* __restrict__ g5,  const void* __restrict__ b5,
                 const void* __restrict__ gs,  const void* __restrict__ bs,
                 const void* __restrict__ gd,  const void* __restrict__ bd) {
    size_t idx = ((size_t)blockIdx.x * 256 + threadIdx.x) * 4;
    int c = (int)((idx >> 10) & (C_ - 1));
    int isf32 = g_isf32;
    float4 o = {0.f, 0.f, 0.f, 0.f};
    float s3 = g_sel[3];
    if (s3 != 0.f) {
        float4 h = *(const float4*)(g_h + idx);
        o.x = s3 * h.x; o.y = s3 * h.y; o.z = s3 * h.z; o.w = s3 * h.w;
    }
    float sv;
    if ((sv = g_sel[1]) != 0.f) bn_term(o, g_pm, idx, c, 1, sv, gmp, bmp, isf32);
    if ((sv = g_sel[2]) != 0.f) bn_term(o, g_pa, idx, c, 2, sv, gap, bap, isf32);
    if ((sv = g_sel[4]) != 0.f) bn_term(o, g_c3, idx, c, 4, sv, g3,  b3,  isf32);
    if ((sv = g_sel[5]) != 0.f) bn_term(o, g_c5, idx, c, 5, sv, g5,  b5,  isf32);
    if ((sv = g_sel[6]) != 0.f) bn_term(o, g_pw, idx, c, 6, sv, gs,  bs,  isf32);
    if ((sv = g_sel[7]) != 0.f) bn_term(o, g_cd, idx, c, 7, sv, gd,  bd,  isf32);
    if (isf32) {
        *(float4*)((float*)out + idx) = o;
    } else {
        ushort4 u; u.x = f2u(o.x); u.y = f2u(o.y); u.z = f2u(o.z); u.w = f2u(o.w);
        *(ushort4*)((unsigned short*)out + idx) = u;
    }
}

// ---------------------------------------------------------------------------
extern "C" void kernel_launch(void* const* d_in, const int* in_sizes, int n_in,
                              void* d_out, int out_size, void* d_ws, size_t ws_size,
                              hipStream_t stream) {
    const void* x    = d_in[0];
    const void* aw   = d_in[1];
    const void* w_in = d_in[2];
    const void* g_in = d_in[3];
    const void* b_in = d_in[4];
    const void* w3   = d_in[5];
    const void* g3   = d_in[6];
    const void* b3   = d_in[7];
    const void* w5   = d_in[8];
    const void* g5   = d_in[9];
    const void* b5   = d_in[10];
    const void* wdw  = d_in[11];
    const void* wpw  = d_in[12];
    const void* gs   = d_in[13];
    const void* bs   = d_in[14];
    const void* wd   = d_in[15];
    const void* gd   = d_in[16];
    const void* bd   = d_in[17];
    const void* gmp  = d_in[18];
    const void* bmp  = d_in[19];
    const void* gap  = d_in[20];
    const void* bap  = d_in[21];

    dim3 Bk(256);
    dim3 Gfull(NB_);    // 16384 per-(b,c) blocks
    dim3 Gc16(1024);    // COUT=16 conv blocks (64 b * 16 cg)

    k_prep<<<dim3(1), Bk, 0, stream>>>(x, aw);
    k_wconv<<<dim3(16), Bk, 0, stream>>>(w3, w5, wd, w_in, wpw);

    // transition: 1x1 conv (COUT=16, no-LDS, named accs) -> g_dw
    k_trans<<<Gc16, Bk, 0, stream>>>(x);

    // fused: BN0+ReLU -> g_h ; pools -> g_pm/g_pa ; depthwise -> g_dw
    k_post<<<Gfull, Bk, 0, stream>>>(g_in, b_in, wdw);

    // ops 4/5/7: specialized dense convs, COUT=16, named accs
    k_conv1<3, 1, 1, 4><<<Gc16, Bk, 0, stream>>>();   // conv3x3   -> g_c3
    k_conv1<5, 1, 2, 5><<<Gc16, Bk, 0, stream>>>();   // conv5x5   -> g_c5
    k_conv1<3, 2, 2, 7><<<Gc16, Bk, 0, stream>>>();   // dil conv  -> g_cd

    // op 6 part 2: pointwise (COUT=16, no-LDS, named accs) -> g_pw
    k_pw<<<Gc16, Bk, 0, stream>>>();

    // single fused epilogue: out = sel3*h + sum sel_k*BN_k(buf_k)
    k_final_all<<<Gfull, Bk, 0, stream>>>(d_out,
        gmp, bmp, gap, bap, g3, b3, g5, b5, gs, bs, gd, bd);
}

// Round 11
// 1246.159 us; speedup vs baseline: 1.4076x; 1.3523x over previous
//
#include <hip/hip_runtime.h>

#define CIN_  128
#define C_    256
#define HW_   1024      /* 32*32 */
#define NPC_  65536.0f  /* 64*1024 elements per channel for BN stats */
#define NB_   16384     /* 64 batches * 256 channels */

constexpr size_t NELEM = 16777216ull;   // 64*256*32*32

// ---- module-scope device scratch: one buffer per producer (no reuse hazards)
__device__ float g_sel[8];
__device__ float g_stats[8 * 512];      // per-slot: [0..255]=sum, [256..511]=sumsq
__device__ int   g_isf32;
__device__ float g_h[NELEM];            // relu(BN0(trans))
__device__ float g_c3[NELEM];           // conv3x3 out      (slot 4)
__device__ float g_c5[NELEM];           // conv5x5 out      (slot 5)
__device__ float g_cd[NELEM];           // dil conv out     (slot 7)
__device__ float g_pm[NELEM];           // maxpool out      (slot 1)
__device__ float g_pa[NELEM];           // avgpool out      (slot 2)
__device__ float g_pw[NELEM];           // pointwise out    (slot 6)
__device__ float g_dw[NELEM];           // trans tmp, then depthwise out

// ---- prepass-converted f32 weights, packed co-fastest (8 per tap) ----------
// g_w5f: [cg=32][ci=256][tap=25][u=8]  (co = cg*8+u)
// g_w3f/g_wdf: [cg=32][ci=256][tap=9][u=8]
// g_wtf: [cg=32][ci=128][u=8]  g_wpf: [cg=32][ci=256][u=8]
__device__ float g_w5f[32 * 256 * 25 * 8];
__device__ float g_w3f[32 * 256 * 9 * 8];
__device__ float g_wdf[32 * 256 * 9 * 8];
__device__ float g_wtf[32 * 128 * 8];
__device__ float g_wpf[32 * 256 * 8];

__device__ __forceinline__ float u2f(unsigned short u) {
    union { unsigned int i; float f; } x; x.i = ((unsigned int)u) << 16; return x.f;
}
__device__ __forceinline__ unsigned short f2u(float f) {
    union { float f; unsigned int i; } x; x.f = f;
    unsigned int r = x.i + 0x7fffu + ((x.i >> 16) & 1u);  // RNE
    return (unsigned short)(r >> 16);
}
__device__ __forceinline__ float ldq(const void* p, long i, int isf32) {
    return isf32 ? ((const float*)p)[i] : u2f(((const unsigned short*)p)[i]);
}

// 32-FMA block shared by k_trans / k_pw (8 output channels x 4 pixels)
#define FMA8X4(acc, wq0, wq1, x0v, x1v, x2v, x3v)                                     \
    acc[0][0] += x0v*wq0.x; acc[0][1] += x1v*wq0.x; acc[0][2] += x2v*wq0.x; acc[0][3] += x3v*wq0.x; \
    acc[1][0] += x0v*wq0.y; acc[1][1] += x1v*wq0.y; acc[1][2] += x2v*wq0.y; acc[1][3] += x3v*wq0.y; \
    acc[2][0] += x0v*wq0.z; acc[2][1] += x1v*wq0.z; acc[2][2] += x2v*wq0.z; acc[2][3] += x3v*wq0.z; \
    acc[3][0] += x0v*wq0.w; acc[3][1] += x1v*wq0.w; acc[3][2] += x2v*wq0.w; acc[3][3] += x3v*wq0.w; \
    acc[4][0] += x0v*wq1.x; acc[4][1] += x1v*wq1.x; acc[4][2] += x2v*wq1.x; acc[4][3] += x3v*wq1.x; \
    acc[5][0] += x0v*wq1.y; acc[5][1] += x1v*wq1.y; acc[5][2] += x2v*wq1.y; acc[5][3] += x3v*wq1.y; \
    acc[6][0] += x0v*wq1.z; acc[6][1] += x1v*wq1.z; acc[6][2] += x2v*wq1.z; acc[6][3] += x3v*wq1.z; \
    acc[7][0] += x0v*wq1.w; acc[7][1] += x1v*wq1.w; acc[7][2] += x2v*wq1.w; acc[7][3] += x3v*wq1.w;

// ---------------------------------------------------------------------------
// prep: zero stats, detect input dtype, compute sel
// ---------------------------------------------------------------------------
__global__ void k_prep(const void* __restrict__ x, const void* __restrict__ aw) {
    __shared__ int flag_s;
    __shared__ float red[256];
    const int t = threadIdx.x;
    for (int i = t; i < 8 * 512; i += 256) g_stats[i] = 0.f;
    const unsigned short* xu = (const unsigned short*)x;
    int bad = 0;
    for (int i = t; i < 8192; i += 256) {
        unsigned int e = (xu[i] >> 7) & 0xFFu;
        if (e >= 0xC6u) ++bad;
    }
    red[t] = (float)bad;
    __syncthreads();
    for (int off = 128; off > 0; off >>= 1) {
        if (t < off) red[t] += red[t + off];
        __syncthreads();
    }
    if (t == 0) { flag_s = (red[0] > 4.0f) ? 1 : 0; g_isf32 = flag_s; }
    __syncthreads();
    const int isf32 = flag_s;
    if (t == 0) {
        float w[8];
        float mx = -1e30f;
        for (int i = 0; i < 8; ++i) { w[i] = ldq(aw, i, isf32); mx = fmaxf(mx, w[i]); }
        float s = 0.f;
        for (int i = 0; i < 8; ++i) { w[i] = expf(w[i] - mx); s += w[i]; }
        for (int i = 0; i < 8; ++i) w[i] /= s;
        float sv[8] = {0,0,0,0,0,0,0,0};
        bool used[8] = {false,false,false,false,false,false,false,false};
        for (int k = 0; k < 3; ++k) {          // top-3, first-index tie-break
            int bi = -1; float bv = -1.f;
            for (int i = 0; i < 8; ++i) if (!used[i] && w[i] > bv) { bv = w[i]; bi = i; }
            used[bi] = true; sv[bi] = bv;
        }
        float tot = 0.f;
        for (int i = 0; i < 8; ++i) { if (sv[i] < 0.01f) sv[i] = 0.f; tot += sv[i]; }
        tot = fmaxf(tot, 1e-12f);
        for (int i = 0; i < 8; ++i) g_sel[i] = sv[i] / tot;
    }
}

// ---------------------------------------------------------------------------
// weight prepass: convert to f32, repack co-fastest (2x float4 per (ci,tap)).
// grid = 32 blocks (cg). Runs after k_prep (needs g_isf32).
// ---------------------------------------------------------------------------
__global__ __launch_bounds__(256)
void k_wconv(const void* __restrict__ w3, const void* __restrict__ w5,
             const void* __restrict__ wd, const void* __restrict__ wi,
             const void* __restrict__ wp) {
    const int cg = blockIdx.x;          // 0..31
    const int t  = threadIdx.x;
    const int isf32 = g_isf32;
    // w5: out o = ((ci*25+tap)*8+u)
    for (int o = t; o < 51200; o += 256) {
        int u = o & 7, r = o >> 3, tap = r % 25, ci = r / 25;
        g_w5f[(size_t)cg * 51200 + o] =
            ldq(w5, ((long)(cg * 8 + u) * C_ + ci) * 25 + tap, isf32);
    }
    // w3 / wd: out o = ((ci*9+tap)*8+u)
    for (int o = t; o < 18432; o += 256) {
        int u = o & 7, r = o >> 3, tap = r % 9, ci = r / 9;
        long ii = ((long)(cg * 8 + u) * C_ + ci) * 9 + tap;
        g_w3f[(size_t)cg * 18432 + o] = ldq(w3, ii, isf32);
        g_wdf[(size_t)cg * 18432 + o] = ldq(wd, ii, isf32);
    }
    // transition weights: [cg][ci=128][u=8]
    for (int o = t; o < 1024; o += 256) {
        int u = o & 7, ci = o >> 3;
        g_wtf[cg * 1024 + o] = ldq(wi, (long)(cg * 8 + u) * CIN_ + ci, isf32);
    }
    // pointwise weights: [cg][ci=256][u=8]
    for (int o = t; o < 2048; o += 256) {
        int u = o & 7, ci = o >> 3;
        g_wpf[cg * 2048 + o] = ldq(wp, (long)(cg * 8 + u) * C_ + ci, isf32);
    }
}

// ---------------------------------------------------------------------------
// stats epilogues
// ---------------------------------------------------------------------------
__device__ __forceinline__ void stats_epilogue(float* red, float s, float s2,
                                               int t, int c, int slot) {
    __syncthreads();
    red[t] = s; red[t + 256] = s2;
    __syncthreads();
    for (int off = 128; off > 0; off >>= 1) {
        if (t < off) { red[t] += red[t + off]; red[t + 256] += red[t + 256 + off]; }
        __syncthreads();
    }
    if (t == 0) {
        atomicAdd(&g_stats[slot * 512 + c], red[0]);
        atomicAdd(&g_stats[slot * 512 + 256 + c], red[256]);
    }
}

__device__ __forceinline__ void stats_ep2(float* red, int t,
                                          float sA, float s2A, float sB, float s2B,
                                          int cA, int cB, int slot) {
    __syncthreads();
    red[t] = sA; red[t + 256] = s2A; red[t + 512] = sB; red[t + 768] = s2B;
    __syncthreads();
    for (int off = 128; off > 0; off >>= 1) {
        if (t < off) {
            red[t]       += red[t + off];
            red[t + 256] += red[t + 256 + off];
            red[t + 512] += red[t + 512 + off];
            red[t + 768] += red[t + 768 + off];
        }
        __syncthreads();
    }
    if (t == 0) {
        atomicAdd(&g_stats[slot * 512 + cA],       red[0]);
        atomicAdd(&g_stats[slot * 512 + 256 + cA], red[256]);
        atomicAdd(&g_stats[slot * 512 + cB],       red[512]);
        atomicAdd(&g_stats[slot * 512 + 256 + cB], red[768]);
    }
}

__device__ __forceinline__ void stats_all8(float* red, int t, float acc[8][4],
                                           int c0, int slot) {
    #pragma unroll
    for (int u = 0; u < 8; u += 2)
        stats_ep2(red, t,
            acc[u][0]+acc[u][1]+acc[u][2]+acc[u][3],
            acc[u][0]*acc[u][0]+acc[u][1]*acc[u][1]+acc[u][2]*acc[u][2]+acc[u][3]*acc[u][3],
            acc[u+1][0]+acc[u+1][1]+acc[u+1][2]+acc[u+1][3],
            acc[u+1][0]*acc[u+1][0]+acc[u+1][1]*acc[u+1][1]+acc[u+1][2]*acc[u+1][2]+acc[u+1][3]*acc[u+1][3],
            c0 + u, c0 + u + 1, slot);
}

// ---------------------------------------------------------------------------
// transition 1x1 conv, COUT=8, NO LDS (direct strided coalesced loads)
// -> g_dw, stats slot 0. grid = 64 b * 32 cgroups = 2048   [R6-proven]
// ---------------------------------------------------------------------------
__global__ __launch_bounds__(256)
void k_trans(const void* __restrict__ xin) {
    __shared__ float red[1024];
    const int t  = threadIdx.x;
    const int cg = blockIdx.x & 31;
    const int c0 = cg * 8;
    const int b  = blockIdx.x >> 5;
    const float* wb = g_wtf + cg * 1024;
    float acc[8][4];
    #pragma unroll
    for (int k = 0; k < 8; ++k)
        #pragma unroll
        for (int j = 0; j < 4; ++j) acc[k][j] = 0.f;

    const size_t base0 = (size_t)b * CIN_ * 1024 + t;
    if (g_isf32) {
        const float* xf = (const float*)xin;
        for (int ci = 0; ci < CIN_; ++ci) {
            const float* xp = xf + base0 + (size_t)ci * 1024;
            float x0v = xp[0], x1v = xp[256], x2v = xp[512], x3v = xp[768];
            float4 wq0 = *(const float4*)(wb + ci * 8);
            float4 wq1 = *(const float4*)(wb + ci * 8 + 4);
            FMA8X4(acc, wq0, wq1, x0v, x1v, x2v, x3v)
        }
    } else {
        const unsigned short* xu = (const unsigned short*)xin;
        for (int ci = 0; ci < CIN_; ++ci) {
            const unsigned short* xp = xu + base0 + (size_t)ci * 1024;
            float x0v = u2f(xp[0]),   x1v = u2f(xp[256]);
            float x2v = u2f(xp[512]), x3v = u2f(xp[768]);
            float4 wq0 = *(const float4*)(wb + ci * 8);
            float4 wq1 = *(const float4*)(wb + ci * 8 + 4);
            FMA8X4(acc, wq0, wq1, x0v, x1v, x2v, x3v)
        }
    }
    #pragma unroll
    for (int k = 0; k < 8; ++k) {
        float* o = g_dw + (size_t)(b * C_ + c0 + k) * HW_;
        o[t] = acc[k][0]; o[t + 256] = acc[k][1];
        o[t + 512] = acc[k][2]; o[t + 768] = acc[k][3];
    }
    stats_all8(red, t, acc, c0, 0);
}

// ---------------------------------------------------------------------------
// FUSED post-transition pass (one per (b,c) channel)  [R10-verified]:
//   h = relu(BN0(g_dw)) -> g_h ; stage h in LDS once;
//   pools (slots 1,2) -> g_pm/g_pa ; depthwise (op 6 part 1) -> g_dw in place.
// Replaces k_bnrelu + k_pool_fused + k_dw (2 fewer launches, ~134 MB less traffic)
// ---------------------------------------------------------------------------
__global__ __launch_bounds__(256)
void k_post(const void* __restrict__ g, const void* __restrict__ bb,
            const void* __restrict__ wdw) {
    __shared__ float xs[34 * 33];
    __shared__ float red[512];
    const int t = threadIdx.x;
    const int c = blockIdx.x & (C_ - 1);
    const int y  = t >> 3;
    const int x0 = (t & 7) * 4;
    const int isf32 = g_isf32;

    // BN0 + ReLU
    float mean = g_stats[c] * (1.0f / NPC_);
    float var  = g_stats[256 + c] * (1.0f / NPC_) - mean * mean;
    float rstd = rsqrtf(fmaxf(var, 0.f) + 1e-5f);
    float gv = ldq(g, c, isf32), bv = ldq(bb, c, isf32);
    float4 r = *(const float4*)(g_dw + (size_t)blockIdx.x * HW_ + t * 4);
    float4 h;
    h.x = fmaxf(0.f, (r.x - mean) * rstd * gv + bv);
    h.y = fmaxf(0.f, (r.y - mean) * rstd * gv + bv);
    h.z = fmaxf(0.f, (r.z - mean) * rstd * gv + bv);
    h.w = fmaxf(0.f, (r.w - mean) * rstd * gv + bv);
    *(float4*)(g_h + (size_t)blockIdx.x * HW_ + t * 4) = h;

    // stage h tile (stride-33)
    float* xw = xs + y * 33 + x0;
    xw[0] = h.x; xw[1] = h.y; xw[2] = h.z; xw[3] = h.w;
    __syncthreads();

    const float s1 = g_sel[1], s2 = g_sel[2], s6 = g_sel[6];

    if (s1 != 0.f || s2 != 0.f) {
        float mx[4] = {0.f, 0.f, 0.f, 0.f};   // h >= 0: matches padded max
        float sm[4] = {0.f, 0.f, 0.f, 0.f};
        #pragma unroll
        for (int ky = 0; ky < 3; ++ky) {
            int iy = y + ky - 1;
            if (iy < 0 || iy >= 32) continue;
            float row[6];
            #pragma unroll
            for (int i = 0; i < 6; ++i) {
                int ix = x0 + i - 1;
                row[i] = (ix >= 0 && ix < 32) ? xs[iy * 33 + ix] : 0.0f;
            }
            #pragma unroll
            for (int kx = 0; kx < 3; ++kx)
                #pragma unroll
                for (int j = 0; j < 4; ++j) {
                    mx[j] = fmaxf(mx[j], row[j + kx]);
                    sm[j] += row[j + kx];
                }
        }
        #pragma unroll
        for (int j = 0; j < 4; ++j) sm[j] *= (1.0f / 9.0f);
        const size_t ob = (size_t)blockIdx.x * HW_ + y * 32 + x0;
        if (s1 != 0.f) {
            float* o = g_pm + ob;
            o[0] = mx[0]; o[1] = mx[1]; o[2] = mx[2]; o[3] = mx[3];
            stats_epilogue(red, mx[0]+mx[1]+mx[2]+mx[3],
                           mx[0]*mx[0]+mx[1]*mx[1]+mx[2]*mx[2]+mx[3]*mx[3], t, c, 1);
        }
        if (s2 != 0.f) {
            float* o = g_pa + ob;
            o[0] = sm[0]; o[1] = sm[1]; o[2] = sm[2]; o[3] = sm[3];
            stats_epilogue(red, sm[0]+sm[1]+sm[2]+sm[3],
                           sm[0]*sm[0]+sm[1]*sm[1]+sm[2]*sm[2]+sm[3]*sm[3], t, c, 2);
        }
    }

    if (s6 != 0.f) {
        float wv[9];
        #pragma unroll
        for (int k = 0; k < 9; ++k) wv[k] = ldq(wdw, (long)c * 9 + k, isf32);
        float acc[4] = {0.f, 0.f, 0.f, 0.f};
        #pragma unroll
        for (int ky = 0; ky < 3; ++ky) {
            int iy = y + ky - 1;
            if (iy < 0 || iy >= 32) continue;
            float row[6];
            #pragma unroll
            for (int i = 0; i < 6; ++i) {
                int ix = x0 + i - 1;
                row[i] = (ix >= 0 && ix < 32) ? xs[iy * 33 + ix] : 0.0f;
            }
            #pragma unroll
            for (int kx = 0; kx < 3; ++kx)
                #pragma unroll
                for (int j = 0; j < 4; ++j)
                    acc[j] += row[j + kx] * wv[ky * 3 + kx];
        }
        float* o = g_dw + (size_t)blockIdx.x * HW_ + y * 32 + x0;
        o[0] = acc[0]; o[1] = acc[1]; o[2] = acc[2]; o[3] = acc[3];
    }
}

// ---------------------------------------------------------------------------
// SPECIALIZED dense conv, COUT=8, WAVE-PRIVATE zero-padded LDS tiles,
// ZERO barriers in the main loop (waves fully decoupled; per-wave dbuf).
// grid = 64 b * 32 cg = 2048.  [R6-proven: VGPR=40, 771 us, VALUBusy 82%]
// ---------------------------------------------------------------------------
template<int KS, int DIL, int PAD, int SLOT>
__global__ __launch_bounds__(256)
void k_conv1() {
    if (g_sel[SLOT] == 0.0f) return;
    constexpr int TRW  = 8 + 2 * PAD;       // wave tile rows (incl. halo)
    constexpr int TAPS = KS * KS;
    __shared__ float xs[4][2][TRW * 40];
    const int t  = threadIdx.x;
    const int w  = t >> 6;                   // wave 0..3
    const int l  = t & 63;
    const int cg = blockIdx.x & 31;
    const int c0 = cg * 8;
    const int b  = blockIdx.x >> 5;
    const int y  = l >> 3;                   // wave-local row 0..7
    const int x0 = (l & 7) * 4;
    const int y0 = w * 8;                    // wave's first output row
    const float* hb = g_h + (size_t)b * C_ * HW_;
    const float* wb = (SLOT == 4 ? g_w3f : SLOT == 5 ? g_w5f : g_wdf)
                      + (size_t)cg * (C_ * TAPS * 8);
    float* obuf = (SLOT == 4) ? g_c3 : (SLOT == 5) ? g_c5 : g_cd;

    // each lane stages tile row y (always) and tile row y+8 (if y < 2*PAD)
    const int grA = y0 - PAD + y;            // global row of tile row y
    const bool okA = (grA >= 0) && (grA < 32);
    const int grB = grA + 8;                 // global row of tile row y+8
    const bool okB = (y < 2 * PAD) && (grB < 32);

    float acc[8][4];
    #pragma unroll
    for (int u = 0; u < 8; ++u)
        #pragma unroll
        for (int j = 0; j < 4; ++j) acc[u][j] = 0.f;

    // zero wave-private double buffer (halo/pad stays zero forever)
    {
        float* xw = &xs[w][0][0];
        for (int i = l; i < 2 * TRW * 40; i += 64) xw[i] = 0.f;
    }
    // prologue: stage ci=0 (same-wave LDS ordering; no barrier needed)
    if (okA) *(float4*)(&xs[w][0][y * 40 + 4 + x0]) =
        *(const float4*)(hb + (size_t)grA * 32 + x0);
    if (okB) *(float4*)(&xs[w][0][(y + 8) * 40 + 4 + x0]) =
        *(const float4*)(hb + (size_t)grB * 32 + x0);
    int cur = 0;

    for (int ci = 0; ci < C_; ++ci) {
        // issue next-channel loads EARLY (hide under FMA body)
        float4 rA = {0.f,0.f,0.f,0.f}, rB = {0.f,0.f,0.f,0.f};
        if (ci + 1 < C_) {
            const float* hn = hb + (size_t)(ci + 1) * HW_;
            if (okA) rA = *(const float4*)(hn + grA * 32 + x0);
            if (okB) rB = *(const float4*)(hn + grB * 32 + x0);
        }
        const float* xsc = xs[w][cur];
        const float* wc  = wb + ci * (TAPS * 8);
        #pragma unroll
        for (int ky = 0; ky < KS; ++ky) {
            const int rr = (y + ky * DIL) * 40 + x0;
            // minimal aligned window reads from the zero-padded tile
            float wnd[12];
            if (PAD == 1) {                 // tile cols x0+3..x0+8
                wnd[3] = xsc[rr + 3];
                float4 qb = *(const float4*)(xsc + rr + 4);
                wnd[4] = qb.x; wnd[5] = qb.y; wnd[6] = qb.z; wnd[7] = qb.w;
                wnd[8] = xsc[rr + 8];
            } else {                        // tile cols x0+2..x0+9
                float2 qa = *(const float2*)(xsc + rr + 2);
                float4 qb = *(const float4*)(xsc + rr + 4);
                float2 qc = *(const float2*)(xsc + rr + 8);
                wnd[2] = qa.x; wnd[3] = qa.y;
                wnd[4] = qb.x; wnd[5] = qb.y; wnd[6] = qb.z; wnd[7] = qb.w;
                wnd[8] = qc.x; wnd[9] = qc.y;
            }
            #pragma unroll
            for (int kx = 0; kx < KS; ++kx) {
                const float4 wA = *(const float4*)(wc + (ky * KS + kx) * 8);
                const float4 wB = *(const float4*)(wc + (ky * KS + kx) * 8 + 4);
                #pragma unroll
                for (int j = 0; j < 4; ++j) {
                    const float v = wnd[(4 - PAD) + j + kx * DIL];
                    acc[0][j] += v * wA.x; acc[1][j] += v * wA.y;
                    acc[2][j] += v * wA.z; acc[3][j] += v * wA.w;
                    acc[4][j] += v * wB.x; acc[5][j] += v * wB.y;
                    acc[6][j] += v * wB.z; acc[7][j] += v * wB.w;
                }
            }
        }
        // write-late into the other wave-private buffer (no barrier)
        if (ci + 1 < C_) {
            float* xn = xs[w][cur ^ 1];
            if (okA) *(float4*)(xn + y * 40 + 4 + x0) = rA;
            if (okB) *(float4*)(xn + (y + 8) * 40 + 4 + x0) = rB;
        }
        cur ^= 1;
    }

    #pragma unroll
    for (int u = 0; u < 8; ++u) {
        float4 o; o.x = acc[u][0]; o.y = acc[u][1]; o.z = acc[u][2]; o.w = acc[u][3];
        *(float4*)(obuf + (size_t)(b * C_ + c0 + u) * HW_ + (y0 + y) * 32 + x0) = o;
    }
    // stats: alias red onto xs (safe: stats_ep2 starts with __syncthreads,
    // so every wave's LDS reads are complete before any red write)
    float* red = &xs[0][0][0];
    stats_all8(red, t, acc, c0, SLOT);
}

// ---------------------------------------------------------------------------
// pointwise 1x1 conv on g_dw, COUT=8, NO LDS (direct strided global loads),
// packed f32 weights -> g_pw + fused stats slot 6   [R6-proven]
// ---------------------------------------------------------------------------
__global__ __launch_bounds__(256)
void k_pw() {
    if (g_sel[6] == 0.0f) return;
    __shared__ float red[1024];
    const int t  = threadIdx.x;
    const int cg = blockIdx.x & 31;
    const int c0 = cg * 8;
    const int b  = blockIdx.x >> 5;
    const float* hb = g_dw + (size_t)b * C_ * HW_ + t;
    const float* wb = g_wpf + cg * 2048;
    float acc[8][4];
    #pragma unroll
    for (int k = 0; k < 8; ++k)
        #pragma unroll
        for (int j = 0; j < 4; ++j) acc[k][j] = 0.f;
    for (int ci = 0; ci < C_; ++ci) {
        const float* hp = hb + (size_t)ci * HW_;
        float x0v = hp[0], x1v = hp[256], x2v = hp[512], x3v = hp[768];
        float4 wq0 = *(const float4*)(wb + ci * 8);
        float4 wq1 = *(const float4*)(wb + ci * 8 + 4);
        FMA8X4(acc, wq0, wq1, x0v, x1v, x2v, x3v)
    }
    #pragma unroll
    for (int k = 0; k < 8; ++k) {
        float* o = g_pw + (size_t)(b * C_ + c0 + k) * HW_;
        o[t] = acc[k][0]; o[t + 256] = acc[k][1];
        o[t + 512] = acc[k][2]; o[t + 768] = acc[k][3];
    }
    stats_all8(red, t, acc, c0, 6);
}

// ---------------------------------------------------------------------------
// single fused epilogue: out = sel3*h + Σ sel_k * BN_k(buf_k), dtype-dual
// ---------------------------------------------------------------------------
__device__ __forceinline__ void bn_term(float4& o, const float* buf, size_t idx,
                                        int c, int slot, float sv,
                                        const void* g, const void* bb, int isf32) {
    float mean = g_stats[slot * 512 + c] * (1.0f / NPC_);
    float var  = g_stats[slot * 512 + 256 + c] * (1.0f / NPC_) - mean * mean;
    float rstd = rsqrtf(fmaxf(var, 0.f) + 1e-5f);
    float gv = ldq(g, c, isf32), bv = ldq(bb, c, isf32);
    float4 r = *(const float4*)(buf + idx);
    o.x += sv * ((r.x - mean) * rstd * gv + bv);
    o.y += sv * ((r.y - mean) * rstd * gv + bv);
    o.z += sv * ((r.z - mean) * rstd * gv + bv);
    o.w += sv * ((r.w - mean) * rstd * gv + bv);
}

__global__ __launch_bounds__(256)
void k_final_all(void* __restrict__ out,
                 const void* __restrict__ gmp, const void* __restrict__ bmp,
                 const void* __restrict__ gap, const void* __restrict__ bap,
                 const void* __restrict__ g3,  const void* __restrict__ b3,
                 const void* __restrict__ g5,  const void* __restrict__ b5,
                 const void* __restrict__ gs,  const void* __restrict__ bs,
                 const void* __restrict__ gd,  const void* __restrict__ bd) {
    size_t idx = ((size_t)blockIdx.x * 256 + threadIdx.x) * 4;
    int c = (int)((idx >> 10) & (C_ - 1));
    int isf32 = g_isf32;
    float4 o = {0.f, 0.f, 0.f, 0.f};
    float s3 = g_sel[3];
    if (s3 != 0.f) {
        float4 h = *(const float4*)(g_h + idx);
        o.x = s3 * h.x; o.y = s3 * h.y; o.z = s3 * h.z; o.w = s3 * h.w;
    }
    float sv;
    if ((sv = g_sel[1]) != 0.f) bn_term(o, g_pm, idx, c, 1, sv, gmp, bmp, isf32);
    if ((sv = g_sel[2]) != 0.f) bn_term(o, g_pa, idx, c, 2, sv, gap, bap, isf32);
    if ((sv = g_sel[4]) != 0.f) bn_term(o, g_c3, idx, c, 4, sv, g3,  b3,  isf32);
    if ((sv = g_sel[5]) != 0.f) bn_term(o, g_c5, idx, c, 5, sv, g5,  b5,  isf32);
    if ((sv = g_sel[6]) != 0.f) bn_term(o, g_pw, idx, c, 6, sv, gs,  bs,  isf32);
    if ((sv = g_sel[7]) != 0.f) bn_term(o, g_cd, idx, c, 7, sv, gd,  bd,  isf32);
    if (isf32) {
        *(float4*)((float*)out + idx) = o;
    } else {
        ushort4 u; u.x = f2u(o.x); u.y = f2u(o.y); u.z = f2u(o.z); u.w = f2u(o.w);
        *(ushort4*)((unsigned short*)out + idx) = u;
    }
}

// ---------------------------------------------------------------------------
extern "C" void kernel_launch(void* const* d_in, const int* in_sizes, int n_in,
                              void* d_out, int out_size, void* d_ws, size_t ws_size,
                              hipStream_t stream) {
    const void* x    = d_in[0];
    const void* aw   = d_in[1];
    const void* w_in = d_in[2];
    const void* g_in = d_in[3];
    const void* b_in = d_in[4];
    const void* w3   = d_in[5];
    const void* g3   = d_in[6];
    const void* b3   = d_in[7];
    const void* w5   = d_in[8];
    const void* g5   = d_in[9];
    const void* b5   = d_in[10];
    const void* wdw  = d_in[11];
    const void* wpw  = d_in[12];
    const void* gs   = d_in[13];
    const void* bs   = d_in[14];
    const void* wd   = d_in[15];
    const void* gd   = d_in[16];
    const void* bd   = d_in[17];
    const void* gmp  = d_in[18];
    const void* bmp  = d_in[19];
    const void* gap  = d_in[20];
    const void* bap  = d_in[21];

    dim3 Bk(256);
    dim3 Gfull(NB_);    // 16384 per-(b,c) blocks
    dim3 Gc8(2048);     // COUT=8 conv blocks (64 b * 32 cg)

    k_prep<<<dim3(1), Bk, 0, stream>>>(x, aw);
    k_wconv<<<dim3(32), Bk, 0, stream>>>(w3, w5, wd, w_in, wpw);

    // transition: 1x1 conv (COUT=8, no-LDS) -> g_dw
    k_trans<<<Gc8, Bk, 0, stream>>>(x);

    // fused: BN0+ReLU -> g_h ; pools -> g_pm/g_pa ; depthwise -> g_dw
    k_post<<<Gfull, Bk, 0, stream>>>(g_in, b_in, wdw);

    // ops 4/5/7: specialized dense convs, COUT=8, wave-private pipeline
    k_conv1<3, 1, 1, 4><<<Gc8, Bk, 0, stream>>>();   // conv3x3   -> g_c3
    k_conv1<5, 1, 2, 5><<<Gc8, Bk, 0, stream>>>();   // conv5x5   -> g_c5
    k_conv1<3, 2, 2, 7><<<Gc8, Bk, 0, stream>>>();   // dil conv  -> g_cd

    // op 6 part 2: pointwise (COUT=8, no-LDS) -> g_pw
    k_pw<<<Gc8, Bk, 0, stream>>>();

    // single fused epilogue: out = sel3*h + sum sel_k*BN_k(buf_k)
    k_final_all<<<Gfull, Bk, 0, stream>>>(d_out,
        gmp, bmp, gap, bap, g3, b3, g5, b5, gs, bs, gd, bd);
}

// Round 12
// 994.729 us; speedup vs baseline: 1.7634x; 1.2528x over previous
//
#include <hip/hip_runtime.h>

#define CIN_  128
#define C_    256
#define CP_   128       /* channel pairs */
#define HW_   1024      /* 32*32 */
#define NPC_  65536.0f  /* 64*1024 elements per channel for BN stats */
#define NB_   16384     /* 64 batches * 256 channels */

constexpr size_t NELEM = 16777216ull;   // 64*256*32*32

// ---- module-scope device scratch ------------------------------------------
__device__ float g_sel[8];
__device__ float g_stats[8 * 512];      // per-slot: [0..255]=sum, [256..511]=sumsq
__device__ int   g_isf32;
__device__ float g_h[NELEM];            // relu(BN0(trans)) f32 (skip term)
__device__ float g_c3[NELEM];           // conv3x3 out      (slot 4)
__device__ float g_c5[NELEM];           // conv5x5 out      (slot 5)
__device__ float g_cd[NELEM];           // dil conv out     (slot 7)
__device__ float g_pm[NELEM];           // maxpool out      (slot 1)
__device__ float g_pa[NELEM];           // avgpool out      (slot 2)
__device__ float g_pw[NELEM];           // pointwise out    (slot 6)
__device__ float g_dw[NELEM];           // trans output (f32)
__device__ unsigned int g_h2[NELEM / 2];   // f16x2-packed h, adjacent-channel pairs
__device__ unsigned int g_dw2[NELEM / 2];  // f16x2-packed depthwise out

// ---- prepass weights ------------------------------------------------------
// f32 for trans: g_wtf [cg=32][ci=128][u=8]
// f16x2-packed for convs/pw: [cg=32][cp=128][tap][u=8] (u32 = {w[2cp], w[2cp+1]})
__device__ float        g_wtf[32 * 128 * 8];
__device__ unsigned int g_w5h[32 * 128 * 25 * 8];
__device__ unsigned int g_w3h[32 * 128 * 9 * 8];
__device__ unsigned int g_wdh[32 * 128 * 9 * 8];
__device__ unsigned int g_wph[32 * 128 * 8];

typedef _Float16 h2v __attribute__((ext_vector_type(2)));

__device__ __forceinline__ h2v u2h2(unsigned int u) {
    union { unsigned int u; h2v h; } x; x.u = u; return x.h;
}
__device__ __forceinline__ unsigned int packh2(float lo, float hi) {
    union { h2v h; unsigned int u; } x;
    x.h[0] = (_Float16)lo; x.h[1] = (_Float16)hi; return x.u;
}
#define DOT2(A, V, W) A = __builtin_amdgcn_fdot2(u2h2(V), u2h2(W), A, false);

__device__ __forceinline__ float u2f(unsigned short u) {
    union { unsigned int i; float f; } x; x.i = ((unsigned int)u) << 16; return x.f;
}
__device__ __forceinline__ unsigned short f2u(float f) {
    union { float f; unsigned int i; } x; x.f = f;
    unsigned int r = x.i + 0x7fffu + ((x.i >> 16) & 1u);  // RNE
    return (unsigned short)(r >> 16);
}
__device__ __forceinline__ float ldq(const void* p, long i, int isf32) {
    return isf32 ? ((const float*)p)[i] : u2f(((const unsigned short*)p)[i]);
}

// 32-FMA block for k_trans (8 output channels x 4 pixels, f32)
#define FMA8X4(acc, wq0, wq1, x0v, x1v, x2v, x3v)                                     \
    acc[0][0] += x0v*wq0.x; acc[0][1] += x1v*wq0.x; acc[0][2] += x2v*wq0.x; acc[0][3] += x3v*wq0.x; \
    acc[1][0] += x0v*wq0.y; acc[1][1] += x1v*wq0.y; acc[1][2] += x2v*wq0.y; acc[1][3] += x3v*wq0.y; \
    acc[2][0] += x0v*wq0.z; acc[2][1] += x1v*wq0.z; acc[2][2] += x2v*wq0.z; acc[2][3] += x3v*wq0.z; \
    acc[3][0] += x0v*wq0.w; acc[3][1] += x1v*wq0.w; acc[3][2] += x2v*wq0.w; acc[3][3] += x3v*wq0.w; \
    acc[4][0] += x0v*wq1.x; acc[4][1] += x1v*wq1.x; acc[4][2] += x2v*wq1.x; acc[4][3] += x3v*wq1.x; \
    acc[5][0] += x0v*wq1.y; acc[5][1] += x1v*wq1.y; acc[5][2] += x2v*wq1.y; acc[5][3] += x3v*wq1.y; \
    acc[6][0] += x0v*wq1.z; acc[6][1] += x1v*wq1.z; acc[6][2] += x2v*wq1.z; acc[6][3] += x3v*wq1.z; \
    acc[7][0] += x0v*wq1.w; acc[7][1] += x1v*wq1.w; acc[7][2] += x2v*wq1.w; acc[7][3] += x3v*wq1.w;

// ---------------------------------------------------------------------------
// prep: zero stats, detect input dtype, compute sel
// ---------------------------------------------------------------------------
__global__ void k_prep(const void* __restrict__ x, const void* __restrict__ aw) {
    __shared__ int flag_s;
    __shared__ float red[256];
    const int t = threadIdx.x;
    for (int i = t; i < 8 * 512; i += 256) g_stats[i] = 0.f;
    const unsigned short* xu = (const unsigned short*)x;
    int bad = 0;
    for (int i = t; i < 8192; i += 256) {
        unsigned int e = (xu[i] >> 7) & 0xFFu;
        if (e >= 0xC6u) ++bad;
    }
    red[t] = (float)bad;
    __syncthreads();
    for (int off = 128; off > 0; off >>= 1) {
        if (t < off) red[t] += red[t + off];
        __syncthreads();
    }
    if (t == 0) { flag_s = (red[0] > 4.0f) ? 1 : 0; g_isf32 = flag_s; }
    __syncthreads();
    const int isf32 = flag_s;
    if (t == 0) {
        float w[8];
        float mx = -1e30f;
        for (int i = 0; i < 8; ++i) { w[i] = ldq(aw, i, isf32); mx = fmaxf(mx, w[i]); }
        float s = 0.f;
        for (int i = 0; i < 8; ++i) { w[i] = expf(w[i] - mx); s += w[i]; }
        for (int i = 0; i < 8; ++i) w[i] /= s;
        float sv[8] = {0,0,0,0,0,0,0,0};
        bool used[8] = {false,false,false,false,false,false,false,false};
        for (int k = 0; k < 3; ++k) {          // top-3, first-index tie-break
            int bi = -1; float bv = -1.f;
            for (int i = 0; i < 8; ++i) if (!used[i] && w[i] > bv) { bv = w[i]; bi = i; }
            used[bi] = true; sv[bi] = bv;
        }
        float tot = 0.f;
        for (int i = 0; i < 8; ++i) { if (sv[i] < 0.01f) sv[i] = 0.f; tot += sv[i]; }
        tot = fmaxf(tot, 1e-12f);
        for (int i = 0; i < 8; ++i) g_sel[i] = sv[i] / tot;
    }
}

// ---------------------------------------------------------------------------
// weight prepass: trans -> f32 packed; convs/pw -> f16x2 channel-pair packed.
// grid = 32 blocks (cg).
// ---------------------------------------------------------------------------
__global__ __launch_bounds__(256)
void k_wconv(const void* __restrict__ w3, const void* __restrict__ w5,
             const void* __restrict__ wd, const void* __restrict__ wi,
             const void* __restrict__ wp) {
    const int cg = blockIdx.x;          // 0..31
    const int t  = threadIdx.x;
    const int isf32 = g_isf32;
    // w5 packed: o = ((cp*25+tap)*8+u)
    for (int o = t; o < 25600; o += 256) {
        int u = o & 7, r = o >> 3, tap = r % 25, cp = r / 25;
        long i0 = ((long)(cg * 8 + u) * C_ + 2 * cp) * 25 + tap;
        long i1 = ((long)(cg * 8 + u) * C_ + 2 * cp + 1) * 25 + tap;
        g_w5h[(size_t)cg * 25600 + o] = packh2(ldq(w5, i0, isf32), ldq(w5, i1, isf32));
    }
    // w3 / wd packed: o = ((cp*9+tap)*8+u)
    for (int o = t; o < 9216; o += 256) {
        int u = o & 7, r = o >> 3, tap = r % 9, cp = r / 9;
        long i0 = ((long)(cg * 8 + u) * C_ + 2 * cp) * 9 + tap;
        long i1 = ((long)(cg * 8 + u) * C_ + 2 * cp + 1) * 9 + tap;
        g_w3h[(size_t)cg * 9216 + o] = packh2(ldq(w3, i0, isf32), ldq(w3, i1, isf32));
        g_wdh[(size_t)cg * 9216 + o] = packh2(ldq(wd, i0, isf32), ldq(wd, i1, isf32));
    }
    // transition weights f32: [cg][ci=128][u=8]
    for (int o = t; o < 1024; o += 256) {
        int u = o & 7, ci = o >> 3;
        g_wtf[cg * 1024 + o] = ldq(wi, (long)(cg * 8 + u) * CIN_ + ci, isf32);
    }
    // pw packed: o = (cp*8+u)
    for (int o = t; o < 1024; o += 256) {
        int u = o & 7, cp = o >> 3;
        long i0 = (long)(cg * 8 + u) * C_ + 2 * cp;
        g_wph[cg * 1024 + o] = packh2(ldq(wp, i0, isf32), ldq(wp, i0 + 1, isf32));
    }
}

// ---------------------------------------------------------------------------
// stats epilogues
// ---------------------------------------------------------------------------
__device__ __forceinline__ void stats_ep2(float* red, int t,
                                          float sA, float s2A, float sB, float s2B,
                                          int cA, int cB, int slot) {
    __syncthreads();
    red[t] = sA; red[t + 256] = s2A; red[t + 512] = sB; red[t + 768] = s2B;
    __syncthreads();
    for (int off = 128; off > 0; off >>= 1) {
        if (t < off) {
            red[t]       += red[t + off];
            red[t + 256] += red[t + 256 + off];
            red[t + 512] += red[t + 512 + off];
            red[t + 768] += red[t + 768 + off];
        }
        __syncthreads();
    }
    if (t == 0) {
        atomicAdd(&g_stats[slot * 512 + cA],       red[0]);
        atomicAdd(&g_stats[slot * 512 + 256 + cA], red[256]);
        atomicAdd(&g_stats[slot * 512 + cB],       red[512]);
        atomicAdd(&g_stats[slot * 512 + 256 + cB], red[768]);
    }
}

__device__ __forceinline__ void stats_all8(float* red, int t, float acc[8][4],
                                           int c0, int slot) {
    #pragma unroll
    for (int u = 0; u < 8; u += 2)
        stats_ep2(red, t,
            acc[u][0]+acc[u][1]+acc[u][2]+acc[u][3],
            acc[u][0]*acc[u][0]+acc[u][1]*acc[u][1]+acc[u][2]*acc[u][2]+acc[u][3]*acc[u][3],
            acc[u+1][0]+acc[u+1][1]+acc[u+1][2]+acc[u+1][3],
            acc[u+1][0]*acc[u+1][0]+acc[u+1][1]*acc[u+1][1]+acc[u+1][2]*acc[u+1][2]+acc[u+1][3]*acc[u+1][3],
            c0 + u, c0 + u + 1, slot);
}

// ---------------------------------------------------------------------------
// transition 1x1 conv, COUT=8, NO LDS -> g_dw, stats slot 0. [R6-proven]
// grid = 64 b * 32 cgroups = 2048
// ---------------------------------------------------------------------------
__global__ __launch_bounds__(256)
void k_trans(const void* __restrict__ xin) {
    __shared__ float red[1024];
    const int t  = threadIdx.x;
    const int cg = blockIdx.x & 31;
    const int c0 = cg * 8;
    const int b  = blockIdx.x >> 5;
    const float* wb = g_wtf + cg * 1024;
    float acc[8][4];
    #pragma unroll
    for (int k = 0; k < 8; ++k)
        #pragma unroll
        for (int j = 0; j < 4; ++j) acc[k][j] = 0.f;

    const size_t base0 = (size_t)b * CIN_ * 1024 + t;
    if (g_isf32) {
        const float* xf = (const float*)xin;
        for (int ci = 0; ci < CIN_; ++ci) {
            const float* xp = xf + base0 + (size_t)ci * 1024;
            float x0v = xp[0], x1v = xp[256], x2v = xp[512], x3v = xp[768];
            float4 wq0 = *(const float4*)(wb + ci * 8);
            float4 wq1 = *(const float4*)(wb + ci * 8 + 4);
            FMA8X4(acc, wq0, wq1, x0v, x1v, x2v, x3v)
        }
    } else {
        const unsigned short* xu = (const unsigned short*)xin;
        for (int ci = 0; ci < CIN_; ++ci) {
            const unsigned short* xp = xu + base0 + (size_t)ci * 1024;
            float x0v = u2f(xp[0]),   x1v = u2f(xp[256]);
            float x2v = u2f(xp[512]), x3v = u2f(xp[768]);
            float4 wq0 = *(const float4*)(wb + ci * 8);
            float4 wq1 = *(const float4*)(wb + ci * 8 + 4);
            FMA8X4(acc, wq0, wq1, x0v, x1v, x2v, x3v)
        }
    }
    #pragma unroll
    for (int k = 0; k < 8; ++k) {
        float* o = g_dw + (size_t)(b * C_ + c0 + k) * HW_;
        o[t] = acc[k][0]; o[t + 256] = acc[k][1];
        o[t + 512] = acc[k][2]; o[t + 768] = acc[k][3];
    }
    stats_all8(red, t, acc, c0, 0);
}

// ---------------------------------------------------------------------------
// FUSED post pass, TWO channels per block (channel pair cp):
//   h = relu(BN0(g_dw)) for c0,c0+1 -> g_h (f32) + g_h2 (f16x2 packed);
//   pools -> g_pm/g_pa (both channels); depthwise -> g_dw2 (f16x2 packed).
// grid = 64 b * 128 cp = 8192
// ---------------------------------------------------------------------------
__global__ __launch_bounds__(256)
void k_post(const void* __restrict__ g, const void* __restrict__ bb,
            const void* __restrict__ wdw) {
    __shared__ float xs0[34 * 33];
    __shared__ float xs1[34 * 33];
    __shared__ float red[1024];
    const int t  = threadIdx.x;
    const int cp = blockIdx.x & 127;
    const int c0 = cp * 2;
    const int b  = blockIdx.x >> 7;
    const int y  = t >> 3;
    const int x0 = (t & 7) * 4;
    const int isf32 = g_isf32;

    // BN0 + ReLU for both channels
    float mean0 = g_stats[c0] * (1.0f / NPC_);
    float var0  = g_stats[256 + c0] * (1.0f / NPC_) - mean0 * mean0;
    float rstd0 = rsqrtf(fmaxf(var0, 0.f) + 1e-5f);
    float gv0 = ldq(g, c0, isf32), bv0 = ldq(bb, c0, isf32);
    float mean1 = g_stats[c0 + 1] * (1.0f / NPC_);
    float var1  = g_stats[256 + c0 + 1] * (1.0f / NPC_) - mean1 * mean1;
    float rstd1 = rsqrtf(fmaxf(var1, 0.f) + 1e-5f);
    float gv1 = ldq(g, c0 + 1, isf32), bv1 = ldq(bb, c0 + 1, isf32);

    const size_t ch0 = (size_t)(b * C_ + c0) * HW_;
    const size_t ch1 = ch0 + HW_;
    float4 r0 = *(const float4*)(g_dw + ch0 + t * 4);
    float4 r1 = *(const float4*)(g_dw + ch1 + t * 4);
    float4 h0, h1;
    h0.x = fmaxf(0.f, (r0.x - mean0) * rstd0 * gv0 + bv0);
    h0.y = fmaxf(0.f, (r0.y - mean0) * rstd0 * gv0 + bv0);
    h0.z = fmaxf(0.f, (r0.z - mean0) * rstd0 * gv0 + bv0);
    h0.w = fmaxf(0.f, (r0.w - mean0) * rstd0 * gv0 + bv0);
    h1.x = fmaxf(0.f, (r1.x - mean1) * rstd1 * gv1 + bv1);
    h1.y = fmaxf(0.f, (r1.y - mean1) * rstd1 * gv1 + bv1);
    h1.z = fmaxf(0.f, (r1.z - mean1) * rstd1 * gv1 + bv1);
    h1.w = fmaxf(0.f, (r1.w - mean1) * rstd1 * gv1 + bv1);
    *(float4*)(g_h + ch0 + t * 4) = h0;
    *(float4*)(g_h + ch1 + t * 4) = h1;
    {   // packed f16x2 h (channel-pair interleaved)
        uint4 hp;
        hp.x = packh2(h0.x, h1.x); hp.y = packh2(h0.y, h1.y);
        hp.z = packh2(h0.z, h1.z); hp.w = packh2(h0.w, h1.w);
        *(uint4*)(g_h2 + ((size_t)(b * CP_) + cp) * HW_ + t * 4) = hp;
    }

    // stage both h tiles (stride-33)
    float* xw0 = xs0 + y * 33 + x0;
    xw0[0] = h0.x; xw0[1] = h0.y; xw0[2] = h0.z; xw0[3] = h0.w;
    float* xw1 = xs1 + y * 33 + x0;
    xw1[0] = h1.x; xw1[1] = h1.y; xw1[2] = h1.z; xw1[3] = h1.w;
    __syncthreads();

    const float s1 = g_sel[1], s2 = g_sel[2], s6 = g_sel[6];

    if (s1 != 0.f || s2 != 0.f) {
        float mx0[4] = {0,0,0,0}, sm0[4] = {0,0,0,0};
        float mx1[4] = {0,0,0,0}, sm1[4] = {0,0,0,0};
        #pragma unroll
        for (int ky = 0; ky < 3; ++ky) {
            int iy = y + ky - 1;
            if (iy < 0 || iy >= 32) continue;
            float row0[6], row1[6];
            #pragma unroll
            for (int i = 0; i < 6; ++i) {
                int ix = x0 + i - 1;
                bool ok = (ix >= 0 && ix < 32);
                row0[i] = ok ? xs0[iy * 33 + ix] : 0.0f;
                row1[i] = ok ? xs1[iy * 33 + ix] : 0.0f;
            }
            #pragma unroll
            for (int kx = 0; kx < 3; ++kx)
                #pragma unroll
                for (int j = 0; j < 4; ++j) {
                    mx0[j] = fmaxf(mx0[j], row0[j + kx]); sm0[j] += row0[j + kx];
                    mx1[j] = fmaxf(mx1[j], row1[j + kx]); sm1[j] += row1[j + kx];
                }
        }
        #pragma unroll
        for (int j = 0; j < 4; ++j) { sm0[j] *= (1.0f / 9.0f); sm1[j] *= (1.0f / 9.0f); }
        const size_t ob0 = ch0 + y * 32 + x0;
        const size_t ob1 = ch1 + y * 32 + x0;
        if (s1 != 0.f) {
            float4 o0; o0.x = mx0[0]; o0.y = mx0[1]; o0.z = mx0[2]; o0.w = mx0[3];
            float4 o1; o1.x = mx1[0]; o1.y = mx1[1]; o1.z = mx1[2]; o1.w = mx1[3];
            *(float4*)(g_pm + ob0) = o0; *(float4*)(g_pm + ob1) = o1;
            stats_ep2(red, t,
                mx0[0]+mx0[1]+mx0[2]+mx0[3],
                mx0[0]*mx0[0]+mx0[1]*mx0[1]+mx0[2]*mx0[2]+mx0[3]*mx0[3],
                mx1[0]+mx1[1]+mx1[2]+mx1[3],
                mx1[0]*mx1[0]+mx1[1]*mx1[1]+mx1[2]*mx1[2]+mx1[3]*mx1[3],
                c0, c0 + 1, 1);
        }
        if (s2 != 0.f) {
            float4 o0; o0.x = sm0[0]; o0.y = sm0[1]; o0.z = sm0[2]; o0.w = sm0[3];
            float4 o1; o1.x = sm1[0]; o1.y = sm1[1]; o1.z = sm1[2]; o1.w = sm1[3];
            *(float4*)(g_pa + ob0) = o0; *(float4*)(g_pa + ob1) = o1;
            stats_ep2(red, t,
                sm0[0]+sm0[1]+sm0[2]+sm0[3],
                sm0[0]*sm0[0]+sm0[1]*sm0[1]+sm0[2]*sm0[2]+sm0[3]*sm0[3],
                sm1[0]+sm1[1]+sm1[2]+sm1[3],
                sm1[0]*sm1[0]+sm1[1]*sm1[1]+sm1[2]*sm1[2]+sm1[3]*sm1[3],
                c0, c0 + 1, 2);
        }
    }

    if (s6 != 0.f) {
        float wv0[9], wv1[9];
        #pragma unroll
        for (int k = 0; k < 9; ++k) {
            wv0[k] = ldq(wdw, (long)c0 * 9 + k, isf32);
            wv1[k] = ldq(wdw, (long)(c0 + 1) * 9 + k, isf32);
        }
        float a0[4] = {0,0,0,0}, a1[4] = {0,0,0,0};
        #pragma unroll
        for (int ky = 0; ky < 3; ++ky) {
            int iy = y + ky - 1;
            if (iy < 0 || iy >= 32) continue;
            float row0[6], row1[6];
            #pragma unroll
            for (int i = 0; i < 6; ++i) {
                int ix = x0 + i - 1;
                bool ok = (ix >= 0 && ix < 32);
                row0[i] = ok ? xs0[iy * 33 + ix] : 0.0f;
                row1[i] = ok ? xs1[iy * 33 + ix] : 0.0f;
            }
            #pragma unroll
            for (int kx = 0; kx < 3; ++kx)
                #pragma unroll
                for (int j = 0; j < 4; ++j) {
                    a0[j] += row0[j + kx] * wv0[ky * 3 + kx];
                    a1[j] += row1[j + kx] * wv1[ky * 3 + kx];
                }
        }
        uint4 dp;
        dp.x = packh2(a0[0], a1[0]); dp.y = packh2(a0[1], a1[1]);
        dp.z = packh2(a0[2], a1[2]); dp.w = packh2(a0[3], a1[3]);
        *(uint4*)(g_dw2 + ((size_t)(b * CP_) + cp) * HW_ + y * 32 + x0) = dp;
    }
}

// ---------------------------------------------------------------------------
// SPECIALIZED dense conv, f16x2 channel-pair packed, dot2 FMA (2 MAC/inst).
// COUT=8, wave-private zero-padded LDS tiles, zero barriers, 128 iterations.
// grid = 64 b * 32 cg = 2048.
// ---------------------------------------------------------------------------
template<int KS, int DIL, int PAD, int SLOT>
__global__ __launch_bounds__(256)
void k_conv1() {
    if (g_sel[SLOT] == 0.0f) return;
    constexpr int TRW  = 8 + 2 * PAD;       // wave tile rows (incl. halo)
    constexpr int TAPS = KS * KS;
    __shared__ unsigned int xs[4][2][TRW * 40];
    const int t  = threadIdx.x;
    const int w  = t >> 6;                   // wave 0..3
    const int l  = t & 63;
    const int cg = blockIdx.x & 31;
    const int c0 = cg * 8;
    const int b  = blockIdx.x >> 5;
    const int y  = l >> 3;                   // wave-local row 0..7
    const int x0 = (l & 7) * 4;
    const int y0 = w * 8;                    // wave's first output row
    const unsigned int* hb = g_h2 + (size_t)b * CP_ * HW_;
    const unsigned int* wb = (SLOT == 4 ? g_w3h : SLOT == 5 ? g_w5h : g_wdh)
                             + (size_t)cg * (CP_ * TAPS * 8);
    float* obuf = (SLOT == 4) ? g_c3 : (SLOT == 5) ? g_c5 : g_cd;

    const int grA = y0 - PAD + y;            // global row of tile row y
    const bool okA = (grA >= 0) && (grA < 32);
    const int grB = grA + 8;                 // global row of tile row y+8
    const bool okB = (y < 2 * PAD) && (grB < 32);

    float acc[8][4];
    #pragma unroll
    for (int u = 0; u < 8; ++u)
        #pragma unroll
        for (int j = 0; j < 4; ++j) acc[u][j] = 0.f;

    {   // zero wave-private double buffer (halo/pad stays zero forever)
        unsigned int* xw = &xs[w][0][0];
        for (int i = l; i < 2 * TRW * 40; i += 64) xw[i] = 0u;
    }
    // prologue: stage cp=0 (same-wave LDS ordering; no barrier needed)
    if (okA) *(uint4*)(&xs[w][0][y * 40 + 4 + x0]) =
        *(const uint4*)(hb + (size_t)grA * 32 + x0);
    if (okB) *(uint4*)(&xs[w][0][(y + 8) * 40 + 4 + x0]) =
        *(const uint4*)(hb + (size_t)grB * 32 + x0);
    int cur = 0;

    for (int cp = 0; cp < CP_; ++cp) {
        // issue next-pair loads EARLY (hide under dot2 body)
        uint4 rA = {0u,0u,0u,0u}, rB = {0u,0u,0u,0u};
        if (cp + 1 < CP_) {
            const unsigned int* hn = hb + (size_t)(cp + 1) * HW_;
            if (okA) rA = *(const uint4*)(hn + grA * 32 + x0);
            if (okB) rB = *(const uint4*)(hn + grB * 32 + x0);
        }
        const unsigned int* xsc = xs[w][cur];
        const unsigned int* wc  = wb + cp * (TAPS * 8);
        #pragma unroll
        for (int ky = 0; ky < KS; ++ky) {
            const int rr = (y + ky * DIL) * 40 + x0;
            // minimal aligned window reads from the zero-padded tile
            unsigned int wnd[12];
            if (PAD == 1) {                 // tile cols x0+3..x0+8
                wnd[3] = xsc[rr + 3];
                uint4 qb = *(const uint4*)(xsc + rr + 4);
                wnd[4] = qb.x; wnd[5] = qb.y; wnd[6] = qb.z; wnd[7] = qb.w;
                wnd[8] = xsc[rr + 8];
            } else {                        // tile cols x0+2..x0+9
                uint2 qa = *(const uint2*)(xsc + rr + 2);
                uint4 qb = *(const uint4*)(xsc + rr + 4);
                uint2 qc = *(const uint2*)(xsc + rr + 8);
                wnd[2] = qa.x; wnd[3] = qa.y;
                wnd[4] = qb.x; wnd[5] = qb.y; wnd[6] = qb.z; wnd[7] = qb.w;
                wnd[8] = qc.x; wnd[9] = qc.y;
            }
            #pragma unroll
            for (int kx = 0; kx < KS; ++kx) {
                const uint4 wA = *(const uint4*)(wc + (ky * KS + kx) * 8);
                const uint4 wB = *(const uint4*)(wc + (ky * KS + kx) * 8 + 4);
                #pragma unroll
                for (int j = 0; j < 4; ++j) {
                    const unsigned int v = wnd[(4 - PAD) + j + kx * DIL];
                    DOT2(acc[0][j], v, wA.x) DOT2(acc[1][j], v, wA.y)
                    DOT2(acc[2][j], v, wA.z) DOT2(acc[3][j], v, wA.w)
                    DOT2(acc[4][j], v, wB.x) DOT2(acc[5][j], v, wB.y)
                    DOT2(acc[6][j], v, wB.z) DOT2(acc[7][j], v, wB.w)
                }
            }
        }
        // write-late into the other wave-private buffer (no barrier)
        if (cp + 1 < CP_) {
            unsigned int* xn = xs[w][cur ^ 1];
            if (okA) *(uint4*)(xn + y * 40 + 4 + x0) = rA;
            if (okB) *(uint4*)(xn + (y + 8) * 40 + 4 + x0) = rB;
        }
        cur ^= 1;
    }

    #pragma unroll
    for (int u = 0; u < 8; ++u) {
        float4 o; o.x = acc[u][0]; o.y = acc[u][1]; o.z = acc[u][2]; o.w = acc[u][3];
        *(float4*)(obuf + (size_t)(b * C_ + c0 + u) * HW_ + (y0 + y) * 32 + x0) = o;
    }
    // stats: alias red onto xs (safe: stats_ep2 starts with __syncthreads)
    float* red = (float*)&xs[0][0][0];
    stats_all8(red, t, acc, c0, SLOT);
}

// ---------------------------------------------------------------------------
// pointwise 1x1 conv on g_dw2 (f16x2 packed), dot2, COUT=8, NO LDS
// -> g_pw + fused stats slot 6. grid = 2048.
// ---------------------------------------------------------------------------
__global__ __launch_bounds__(256)
void k_pw() {
    if (g_sel[6] == 0.0f) return;
    __shared__ float red[1024];
    const int t  = threadIdx.x;
    const int cg = blockIdx.x & 31;
    const int c0 = cg * 8;
    const int b  = blockIdx.x >> 5;
    const unsigned int* hb = g_dw2 + (size_t)b * CP_ * HW_ + t;
    const unsigned int* wb = g_wph + cg * 1024;
    float acc[8][4];
    #pragma unroll
    for (int k = 0; k < 8; ++k)
        #pragma unroll
        for (int j = 0; j < 4; ++j) acc[k][j] = 0.f;
    for (int cp = 0; cp < CP_; ++cp) {
        const unsigned int* hp = hb + (size_t)cp * HW_;
        unsigned int v0 = hp[0], v1 = hp[256], v2 = hp[512], v3 = hp[768];
        uint4 w0 = *(const uint4*)(wb + cp * 8);
        uint4 w1 = *(const uint4*)(wb + cp * 8 + 4);
        DOT2(acc[0][0], v0, w0.x) DOT2(acc[0][1], v1, w0.x) DOT2(acc[0][2], v2, w0.x) DOT2(acc[0][3], v3, w0.x)
        DOT2(acc[1][0], v0, w0.y) DOT2(acc[1][1], v1, w0.y) DOT2(acc[1][2], v2, w0.y) DOT2(acc[1][3], v3, w0.y)
        DOT2(acc[2][0], v0, w0.z) DOT2(acc[2][1], v1, w0.z) DOT2(acc[2][2], v2, w0.z) DOT2(acc[2][3], v3, w0.z)
        DOT2(acc[3][0], v0, w0.w) DOT2(acc[3][1], v1, w0.w) DOT2(acc[3][2], v2, w0.w) DOT2(acc[3][3], v3, w0.w)
        DOT2(acc[4][0], v0, w1.x) DOT2(acc[4][1], v1, w1.x) DOT2(acc[4][2], v2, w1.x) DOT2(acc[4][3], v3, w1.x)
        DOT2(acc[5][0], v0, w1.y) DOT2(acc[5][1], v1, w1.y) DOT2(acc[5][2], v2, w1.y) DOT2(acc[5][3], v3, w1.y)
        DOT2(acc[6][0], v0, w1.z) DOT2(acc[6][1], v1, w1.z) DOT2(acc[6][2], v2, w1.z) DOT2(acc[6][3], v3, w1.z)
        DOT2(acc[7][0], v0, w1.w) DOT2(acc[7][1], v1, w1.w) DOT2(acc[7][2], v2, w1.w) DOT2(acc[7][3], v3, w1.w)
    }
    #pragma unroll
    for (int k = 0; k < 8; ++k) {
        float* o = g_pw + (size_t)(b * C_ + c0 + k) * HW_;
        o[t] = acc[k][0]; o[t + 256] = acc[k][1];
        o[t + 512] = acc[k][2]; o[t + 768] = acc[k][3];
    }
    stats_all8(red, t, acc, c0, 6);
}

// ---------------------------------------------------------------------------
// single fused epilogue: out = sel3*h + Σ sel_k * BN_k(buf_k), dtype-dual
// ---------------------------------------------------------------------------
__device__ __forceinline__ void bn_term(float4& o, const float* buf, size_t idx,
                                        int c, int slot, float sv,
                                        const void* g, const void* bb, int isf32) {
    float mean = g_stats[slot * 512 + c] * (1.0f / NPC_);
    float var  = g_stats[slot * 512 + 256 + c] * (1.0f / NPC_) - mean * mean;
    float rstd = rsqrtf(fmaxf(var, 0.f) + 1e-5f);
    float gv = ldq(g, c, isf32), bv = ldq(bb, c, isf32);
    float4 r = *(const float4*)(buf + idx);
    o.x += sv * ((r.x - mean) * rstd * gv + bv);
    o.y += sv * ((r.y - mean) * rstd * gv + bv);
    o.z += sv * ((r.z - mean) * rstd * gv + bv);
    o.w += sv * ((r.w - mean) * rstd * gv + bv);
}

__global__ __launch_bounds__(256)
void k_final_all(void* __restrict__ out,
                 const void* __restrict__ gmp, const void* __restrict__ bmp,
                 const void* __restrict__ gap, const void* __restrict__ bap,
                 const void* __restrict__ g3,  const void* __restrict__ b3,
                 const void* __restrict__ g5,  const void* __restrict__ b5,
                 const void* __restrict__ gs,  const void* __restrict__ bs,
                 const void* __restrict__ gd,  const void* __restrict__ bd) {
    size_t idx = ((size_t)blockIdx.x * 256 + threadIdx.x) * 4;
    int c = (int)((idx >> 10) & (C_ - 1));
    int isf32 = g_isf32;
    float4 o = {0.f, 0.f, 0.f, 0.f};
    float s3 = g_sel[3];
    if (s3 != 0.f) {
        float4 h = *(const float4*)(g_h + idx);
        o.x = s3 * h.x; o.y = s3 * h.y; o.z = s3 * h.z; o.w = s3 * h.w;
    }
    float sv;
    if ((sv = g_sel[1]) != 0.f) bn_term(o, g_pm, idx, c, 1, sv, gmp, bmp, isf32);
    if ((sv = g_sel[2]) != 0.f) bn_term(o, g_pa, idx, c, 2, sv, gap, bap, isf32);
    if ((sv = g_sel[4]) != 0.f) bn_term(o, g_c3, idx, c, 4, sv, g3,  b3,  isf32);
    if ((sv = g_sel[5]) != 0.f) bn_term(o, g_c5, idx, c, 5, sv, g5,  b5,  isf32);
    if ((sv = g_sel[6]) != 0.f) bn_term(o, g_pw, idx, c, 6, sv, gs,  bs,  isf32);
    if ((sv = g_sel[7]) != 0.f) bn_term(o, g_cd, idx, c, 7, sv, gd,  bd,  isf32);
    if (isf32) {
        *(float4*)((float*)out + idx) = o;
    } else {
        ushort4 u; u.x = f2u(o.x); u.y = f2u(o.y); u.z = f2u(o.z); u.w = f2u(o.w);
        *(ushort4*)((unsigned short*)out + idx) = u;
    }
}

// ---------------------------------------------------------------------------
extern "C" void kernel_launch(void* const* d_in, const int* in_sizes, int n_in,
                              void* d_out, int out_size, void* d_ws, size_t ws_size,
                              hipStream_t stream) {
    const void* x    = d_in[0];
    const void* aw   = d_in[1];
    const void* w_in = d_in[2];
    const void* g_in = d_in[3];
    const void* b_in = d_in[4];
    const void* w3   = d_in[5];
    const void* g3   = d_in[6];
    const void* b3   = d_in[7];
    const void* w5   = d_in[8];
    const void* g5   = d_in[9];
    const void* b5   = d_in[10];
    const void* wdw  = d_in[11];
    const void* wpw  = d_in[12];
    const void* gs   = d_in[13];
    const void* bs   = d_in[14];
    const void* wd   = d_in[15];
    const void* gd   = d_in[16];
    const void* bd   = d_in[17];
    const void* gmp  = d_in[18];
    const void* bmp  = d_in[19];
    const void* gap  = d_in[20];
    const void* bap  = d_in[21];

    dim3 Bk(256);
    dim3 Gfull(NB_);    // 16384 per-(b,c) blocks (k_final)
    dim3 Gc8(2048);     // COUT=8 conv blocks (64 b * 32 cg)
    dim3 Gpost(8192);   // 64 b * 128 channel-pairs

    k_prep<<<dim3(1), Bk, 0, stream>>>(x, aw);
    k_wconv<<<dim3(32), Bk, 0, stream>>>(w3, w5, wd, w_in, wpw);

    // transition: 1x1 conv (COUT=8, no-LDS, f32) -> g_dw
    k_trans<<<Gc8, Bk, 0, stream>>>(x);

    // fused: BN0+ReLU -> g_h/g_h2 ; pools -> g_pm/g_pa ; depthwise -> g_dw2
    k_post<<<Gpost, Bk, 0, stream>>>(g_in, b_in, wdw);

    // ops 4/5/7: dense convs, f16x2-packed dot2, wave-private pipeline
    k_conv1<3, 1, 1, 4><<<Gc8, Bk, 0, stream>>>();   // conv3x3   -> g_c3
    k_conv1<5, 1, 2, 5><<<Gc8, Bk, 0, stream>>>();   // conv5x5   -> g_c5
    k_conv1<3, 2, 2, 7><<<Gc8, Bk, 0, stream>>>();   // dil conv  -> g_cd

    // op 6 part 2: pointwise (dot2 on g_dw2) -> g_pw
    k_pw<<<Gc8, Bk, 0, stream>>>();

    // single fused epilogue: out = sel3*h + sum sel_k*BN_k(buf_k)
    k_final_all<<<Gfull, Bk, 0, stream>>>(d_out,
        gmp, bmp, gap, bap, g3, b3, g5, b5, gs, bs, gd, bd);
}